// Round 1
// 673.602 us; speedup vs baseline: 1.0347x; 1.0347x over previous
//
#include <hip/hip_runtime.h>
#include <hip/hip_bf16.h>
#include <hip/hip_fp8.h>

#define DD   128
#define HH   8

typedef short bf16x8 __attribute__((ext_vector_type(8)));
typedef float f32x4  __attribute__((ext_vector_type(4)));
typedef float f32x2  __attribute__((ext_vector_type(2)));

__device__ __forceinline__ float b2f(unsigned short v){
  union { unsigned int u; float f; } x; x.u = ((unsigned int)v) << 16; return x.f;
}
__device__ __forceinline__ unsigned short f2b(float f){
  __hip_bfloat16 h = __float2bfloat16(f);
  return *(unsigned short*)&h;
}
__device__ __forceinline__ unsigned char f2f8(float x){
  __hip_fp8_e4m3 h(x);
  return h.__x;
}
__device__ __forceinline__ float f82f(unsigned char b){
  __hip_fp8_e4m3 h; h.__x = b;
  return (float)h;
}
// bf16 pair (one u32) -> f32x2
__device__ __forceinline__ f32x2 bfpair(unsigned int g){
  union { unsigned int u; float f; } lo, hi;
  lo.u = g << 16; hi.u = g & 0xffff0000u;
  return (f32x2){lo.f, hi.f};
}
// 8 fp8 bytes (uint2) -> 4 f32x2
__device__ __forceinline__ void cvt8(uint2 w, f32x2* o){
#if defined(__has_builtin)
# if __has_builtin(__builtin_amdgcn_cvt_pk_f32_fp8)
  o[0] = __builtin_amdgcn_cvt_pk_f32_fp8((int)w.x, false);
  o[1] = __builtin_amdgcn_cvt_pk_f32_fp8((int)w.x, true);
  o[2] = __builtin_amdgcn_cvt_pk_f32_fp8((int)w.y, false);
  o[3] = __builtin_amdgcn_cvt_pk_f32_fp8((int)w.y, true);
  return;
# endif
#endif
  o[0] = (f32x2){f82f(w.x&0xff),        f82f((w.x>>8)&0xff)};
  o[1] = (f32x2){f82f((w.x>>16)&0xff),  f82f((w.x>>24)&0xff)};
  o[2] = (f32x2){f82f(w.y&0xff),        f82f((w.y>>8)&0xff)};
  o[3] = (f32x2){f82f((w.y>>16)&0xff),  f82f((w.y>>24)&0xff)};
}
struct __align__(8) us4 { unsigned short x,y,z,w; };

__device__ __forceinline__ float gld(const void* p, size_t i, bool f32){
  if (f32) return ((const float*)p)[i];
  return b2f(((const unsigned short*)p)[i]);
}

// async global->LDS, 16B per lane (wave-uniform LDS base + lane*16)
__device__ __forceinline__ void gll16(const void* g, void* l){
  __builtin_amdgcn_global_load_lds(
      (const __attribute__((address_space(1))) unsigned int*)g,
      (__attribute__((address_space(3))) unsigned int*)l, 16, 0, 0);
}

// ALL weight blocks (8 tensors x NB matrices) -> bf16 TRANSPOSED staging, one launch.
struct WPtrs { const void* p[8]; };
__global__ __launch_bounds__(256) void w_repack16(
    WPtrs W, unsigned short* __restrict__ stage, int NBt,
    const int* __restrict__ dflag)
{
  const bool wf32 = (*dflag) != 0;
  int idx = blockIdx.x >> 6;
  int ti = idx / NBt, bi = idx - ti*NBt;
  size_t bo = (size_t)bi*DD*DD;
  int i = (blockIdx.x & 63)*256 + threadIdx.x;
  int k = i >> 7, n = i & 127;
  float x;
  if (wf32) x = ((const float*)W.p[ti])[bo + i];
  else      x = b2f(((const unsigned short*)W.p[ti])[bo + i]);
  stage[(size_t)idx*DD*DD + n*DD + k] = f2b(x);
}

enum { EPI_STORE=0, EPI_SCALE_CONST=1, EPI_SCALE_GATHER=2, EPI_RELU=3,
       EPI_RELU_RES=4, EPI_RELU_RES2=5 };

#define CPAD 132

// ===== shared GEMM building blocks: linear LDS + XOR chunk swizzle =====
// LDS layout: row r (128 bf16 = 256B = 16 chunks of 16B); logical chunk c is
// stored at chunk c ^ (r&7).  Written either by global_load_lds with the
// inverse-swizzled per-lane GLOBAL address (linear LDS dest), or by ds_write
// at the swizzled offset.  Fragment reads use offset  kk ^ ((am&7)<<3).

// C[M,128] = epi( A[M,128] @ B[128,128] ), B bf16 TRANSPOSED ([n][k]).
// EPI_RELU_RES : C = relu(x) + Rb(bf16)                  [big Wo, OUTB=1]
// EPI_RELU_RES2: Cv = relu(x) f32; C2 = relu(x)+Rf (f32) [meta Wo, OUTB=0]
template<int EPI, bool INB, bool OUTB>
__global__ __launch_bounds__(256) void gemm128m(
    const void* __restrict__ Av, const unsigned short* __restrict__ Bt,
    void* __restrict__ Cv, int M,
    const unsigned short* __restrict__ Rb,
    const float* __restrict__ Rf, float* __restrict__ C2)
{
  __shared__ __align__(16) unsigned short Asb[64*128];
  __shared__ __align__(16) unsigned short Btb[16896];  // B: 32KB / C: 64x132 f32
  const int tid = threadIdx.x;
  const int wave = tid >> 6, lane = tid & 63;
  const int row0 = blockIdx.x * 64;

  if (INB){
    const char* Ab = (const char*)Av;
    int n4 = lane >> 4, c = lane & 15;
#pragma unroll
    for (int op=0; op<4; op++){
      int rA = wave*16 + op*4;
      int n = rA + n4;
      int gr = row0 + n; if (gr >= M) gr = M - 1;
      gll16(Ab + (size_t)gr*256 + ((size_t)((c ^ (n & 7)) << 4)), &Asb[rA*128]);
    }
  } else {
    const float* Af = (const float*)Av;
    int r = tid >> 2, cb = (tid & 3) * 32, rx = (r & 7) << 3;
    int gr = row0 + r;
#pragma unroll
    for (int j=0;j<8;j++){
      int cc = cb + j*4;
      float4 val = make_float4(0.f,0.f,0.f,0.f);
      if (gr < M) val = *(const float4*)(Af + (size_t)gr*DD + cc);
      us4 o; o.x=f2b(val.x); o.y=f2b(val.y); o.z=f2b(val.z); o.w=f2b(val.w);
      *(us4*)&Asb[r*128 + (cc ^ rx)] = o;
    }
  }
  {
    int n4 = lane >> 4, c = lane & 15;
#pragma unroll
    for (int op=0; op<8; op++){
      int rB = wave*32 + op*4;
      int n = rB + n4;
      gll16((const char*)Bt + (size_t)n*256 + ((size_t)((c ^ (n & 7)) << 4)),
            &Btb[rB*128]);
    }
  }
  __syncthreads();

  f32x4 acc[8];
#pragma unroll
  for (int t=0;t<8;t++) acc[t] = (f32x4){0.f,0.f,0.f,0.f};
  const int am = (lane & 15), kq = (lane >> 4) * 8, axr = (am & 7) << 3;
#pragma unroll
  for (int k0=0;k0<128;k0+=32){
    int xo = (k0 + kq) ^ axr;
    bf16x8 a = *(bf16x8*)&Asb[(wave*16 + am)*128 + xo];
#pragma unroll
    for (int t=0;t<8;t++){
      bf16x8 b = *(bf16x8*)&Btb[(t*16 + am)*128 + xo];
      acc[t] = __builtin_amdgcn_mfma_f32_16x16x32_bf16(a, b, acc[t], 0,0,0);
    }
  }
  __syncthreads();
  float* Cls = (float*)Btb;
  {
    int rr = wave*16 + (lane>>4)*4;
    int cc = lane & 15;
#pragma unroll
    for (int t=0;t<8;t++)
#pragma unroll
      for (int r=0;r<4;r++)
        Cls[(rr + r)*CPAD + t*16 + cc] = acc[t][r];
  }
  __syncthreads();

  {
    int r = tid >> 2, cb = (tid & 3) * 32;
    int gr = row0 + r;
    if (gr < M){
#pragma unroll
      for (int j=0;j<8;j++){
        int c = cb + j*4;
        float4 o = *(float4*)&Cls[r*CPAD + c];
        if (EPI == EPI_RELU_RES){
          us4 rb = *(const us4*)(Rb + (size_t)gr*DD + c);
          o.x=fmaxf(o.x,0.f)+b2f(rb.x); o.y=fmaxf(o.y,0.f)+b2f(rb.y);
          o.z=fmaxf(o.z,0.f)+b2f(rb.z); o.w=fmaxf(o.w,0.f)+b2f(rb.w);
        } else if (EPI == EPI_RELU_RES2){
          o.x=fmaxf(o.x,0.f); o.y=fmaxf(o.y,0.f); o.z=fmaxf(o.z,0.f); o.w=fmaxf(o.w,0.f);
          float4 rf = *(const float4*)(Rf + (size_t)gr*DD + c);
          *(float4*)(C2 + (size_t)gr*DD + c) =
              make_float4(o.x+rf.x, o.y+rf.y, o.z+rf.z, o.w+rf.w);
        }
        if (OUTB){
          us4 ob; ob.x=f2b(o.x); ob.y=f2b(o.y); ob.z=f2b(o.z); ob.w=f2b(o.w);
          *(us4*)((unsigned short*)Cv + (size_t)gr*DD + c) = ob;
        } else {
          *(float4*)((float*)Cv + (size_t)gr*DD + c) = o;
        }
      }
    }
  }
}

// Fused Q/K/V gemm. FP8KV: phases 1/2 write fp8 (x8 scale) into 256B/row kv buffer.
template<int EPIQ, bool INB, bool FP8KV>
__global__ __launch_bounds__(256) void gemm_qkv(
    const void* __restrict__ Av,
    const unsigned short* __restrict__ Btq, const unsigned short* __restrict__ Btk,
    const unsigned short* __restrict__ Btv,
    void* __restrict__ Cq, void* __restrict__ Ck, int stK,
    void* __restrict__ Cvo, int stV, int M,
    const float* __restrict__ svec, const float* __restrict__ P2,
    const int* __restrict__ gidx)
{
  __shared__ __align__(16) unsigned short Asb[64*128];
  __shared__ __align__(16) unsigned short Btb[16896];
  const int tid = threadIdx.x;
  const int wave = tid >> 6, lane = tid & 63;
  const int row0 = blockIdx.x * 64;

  if (INB){
    const char* Ab = (const char*)Av;
    int n4 = lane >> 4, c = lane & 15;
#pragma unroll
    for (int op=0; op<4; op++){
      int rA = wave*16 + op*4;
      int n = rA + n4;
      int gr = row0 + n; if (gr >= M) gr = M - 1;
      gll16(Ab + (size_t)gr*256 + ((size_t)((c ^ (n & 7)) << 4)), &Asb[rA*128]);
    }
  } else {
    const float* Af = (const float*)Av;
    int r = tid >> 2, cb = (tid & 3) * 32, rx = (r & 7) << 3;
    int gr = row0 + r;
#pragma unroll
    for (int j=0;j<8;j++){
      int cc = cb + j*4;
      float4 val = make_float4(0.f,0.f,0.f,0.f);
      if (gr < M) val = *(const float4*)(Af + (size_t)gr*DD + cc);
      us4 o; o.x=f2b(val.x); o.y=f2b(val.y); o.z=f2b(val.z); o.w=f2b(val.w);
      *(us4*)&Asb[r*128 + (cc ^ rx)] = o;
    }
  }

  const unsigned short* Bts[3] = {Btq, Btk, Btv};
  void* Cs[3] = {Cq, Ck, Cvo};
  const int sts[3] = {DD, stK, stV};
  const int am = (lane & 15), kq = (lane >> 4) * 8, axr = (am & 7) << 3;

  for (int ph=0; ph<3; ph++){
    {
      const unsigned short* Bt = Bts[ph];
      int n4 = lane >> 4, c = lane & 15;
#pragma unroll
      for (int op=0; op<8; op++){
        int rB = wave*32 + op*4;
        int n = rB + n4;
        gll16((const char*)Bt + (size_t)n*256 + ((size_t)((c ^ (n & 7)) << 4)),
              &Btb[rB*128]);
      }
    }
    __syncthreads();
    f32x4 acc[8];
#pragma unroll
    for (int t=0;t<8;t++) acc[t] = (f32x4){0.f,0.f,0.f,0.f};
#pragma unroll
    for (int k0=0;k0<128;k0+=32){
      int xo = (k0 + kq) ^ axr;
      bf16x8 a = *(bf16x8*)&Asb[(wave*16 + am)*128 + xo];
#pragma unroll
      for (int t=0;t<8;t++){
        bf16x8 b = *(bf16x8*)&Btb[(t*16 + am)*128 + xo];
        acc[t] = __builtin_amdgcn_mfma_f32_16x16x32_bf16(a, b, acc[t], 0,0,0);
      }
    }
    __syncthreads();
    float* Cls = (float*)Btb;
    {
      int rr = wave*16 + (lane>>4)*4;
      int cc = lane & 15;
#pragma unroll
      for (int t=0;t<8;t++)
#pragma unroll
        for (int r=0;r<4;r++)
          Cls[(rr + r)*CPAD + t*16 + cc] = acc[t][r];
    }
    __syncthreads();
    {
      int r = tid >> 2, cb = (tid & 3) * 32;
      int gr = row0 + r;
      if (gr < M){
#pragma unroll
        for (int j=0;j<8;j++){
          int c = cb + j*4;
          float4 o = *(float4*)&Cls[r*CPAD + c];
          if (ph == 0){
            if (EPIQ == EPI_SCALE_GATHER){
              int g = gidx[gr];
              const float* p = P2 + (size_t)g*DD + c;
              o.x*=(svec[c+0]+p[0]); o.y*=(svec[c+1]+p[1]);
              o.z*=(svec[c+2]+p[2]); o.w*=(svec[c+3]+p[3]);
            } else {
              o.x*=svec[c+0]; o.y*=svec[c+1]; o.z*=svec[c+2]; o.w*=svec[c+3];
            }
          }
          if (FP8KV && ph > 0){
            unsigned char* Cb = (unsigned char*)Cs[ph];
            uchar4 ob;
            ob.x=f2f8(o.x*8.f); ob.y=f2f8(o.y*8.f);
            ob.z=f2f8(o.z*8.f); ob.w=f2f8(o.w*8.f);
            *(uchar4*)(Cb + (size_t)gr*256 + c) = ob;
          } else {
            us4 ob; ob.x=f2b(o.x); ob.y=f2b(o.y); ob.z=f2b(o.z); ob.w=f2b(o.w);
            *(us4*)((unsigned short*)Cs[ph] + (size_t)gr*sts[ph] + c) = ob;
          }
        }
      }
    }
    __syncthreads();
  }
}

// Static param-name graph -> base params.  (k_detect fused in.)
__global__ __launch_bounds__(256) void k_static(
    const void* __restrict__ emb, const int* __restrict__ svals,
    const int* __restrict__ ssrc, const int* __restrict__ sdst,
    const void* __restrict__ u, const void* __restrict__ W2,
    const void* __restrict__ W1, float* __restrict__ base, int nsrc,
    int* __restrict__ dflag)
{
  __shared__ float sagg[15][128];
  __shared__ float ssc[15][16];
  __shared__ float sww[15][16];
  __shared__ int swf;
  const int t = threadIdx.x;
  if (t < 64){
    float m = 0.f;
    for (int i=t; i<128; i+=64){
      float x = fabsf(b2f(((const unsigned short*)emb)[i]));
      if (x < 1e30f) m = fmaxf(m, x);
    }
#pragma unroll
    for (int s=1;s<64;s<<=1) m = fmaxf(m, __shfl_xor(m, s, 64));
    if (t==0){ int f = (m > 1e4f) ? 1 : 0; *dflag = f; swf = f; }
  }
  for (int i=t;i<15*128;i+=256) ((float*)sagg)[i]=0.f;
  __syncthreads();
  const bool wf32 = (swf != 0);
  if (t < 128){
    for (int i=0;i<nsrc;i++){
      int row = sdst[i]; int vr = svals[ssrc[i]];
      sagg[row][t] += gld(emb, (size_t)vr*DD + t, wf32);
    }
  }
  __syncthreads();
  if (t < 240){
    int n = t>>4, l = t&15;
    float a=0.f;
    for (int d=0;d<128;d++) a += sagg[n][d]*gld(u, l*128+d, wf32);
    ssc[n][l] = a * 0.08838834764831845f;
  }
  __syncthreads();
  if (t < 15){
    float mx=-1e30f;
    for (int l=0;l<16;l++) mx = fmaxf(mx, ssc[t][l]);
    float s=0.f;
    for (int l=0;l<16;l++){ float e=__expf(ssc[t][l]-mx); sww[t][l]=e; s+=e; }
    float inv = 1.f/s;
    for (int l=0;l<16;l++) sww[t][l]*=inv;
  }
  __syncthreads();
  if (t < 8){
    float a=0.f,b=0.f,c=0.f;
    for (int l=0;l<16;l++){
      float wv = gld(W1, l*8+t, wf32);
      a += sww[0][l]*wv; b += sww[3][l]*wv; c += sww[9][l]*wv;
    }
    base[t]=a; base[8+t]=b; base[16+t]=c;
  }
  if (t < 128){
    float a=0.f,b=0.f;
    for (int l=0;l<16;l++){
      float wv = gld(W2, l*128+t, wf32);
      a += sww[6][l]*wv; b += sww[12][l]*wv;
    }
    base[24+t]=a; base[152+t]=b;
  }
}

// Merged gather: big graph rows -> bf16 feat; meta rows -> f32 meta_feat.
__global__ __launch_bounds__(256) void gather_rows2(
    const void* __restrict__ emb,
    const int* __restrict__ valsB, unsigned short* __restrict__ featB, int nB,
    const int* __restrict__ valsM, float* __restrict__ featM, int nM,
    const int* __restrict__ dflag)
{
  const bool wf32 = (*dflag) != 0;
  int i = blockIdx.x*256 + threadIdx.x;
  bool big = (i < nB*16);
  int i2 = big ? i : (i - nB*16);
  if (!big && i2 >= nM*16) return;
  int r = i2>>4, c = (i2&15)*8;
  int vr = big ? valsB[r] : valsM[r];
  float vb[8];
  if (wf32){
    float4 f0 = *(const float4*)((const float*)emb + (size_t)vr*DD + c);
    float4 f1 = *(const float4*)((const float*)emb + (size_t)vr*DD + c + 4);
    vb[0]=f0.x; vb[1]=f0.y; vb[2]=f0.z; vb[3]=f0.w;
    vb[4]=f1.x; vb[5]=f1.y; vb[6]=f1.z; vb[7]=f1.w;
  } else {
    uint4 raw = *(const uint4*)((const unsigned short*)emb + (size_t)vr*DD + c);
    const unsigned short* hw = (const unsigned short*)&raw;
#pragma unroll
    for (int j=0;j<8;j++) vb[j] = b2f(hw[j]);
  }
  if (big){
    unsigned short* d = featB + (size_t)r*DD + c;
    us4 o0, o1;
    o0.x=f2b(vb[0]); o0.y=f2b(vb[1]); o0.z=f2b(vb[2]); o0.w=f2b(vb[3]);
    o1.x=f2b(vb[4]); o1.y=f2b(vb[5]); o1.z=f2b(vb[6]); o1.w=f2b(vb[7]);
    *(us4*)d = o0; *(us4*)(d+4) = o1;
  } else {
    float* d = featM + (size_t)r*DD + c;
    *(float4*)d     = make_float4(vb[0],vb[1],vb[2],vb[3]);
    *(float4*)(d+4) = make_float4(vb[4],vb[5],vb[6],vb[7]);
  }
}

__global__ __launch_bounds__(256) void zeroi(int* __restrict__ p, int n){
  int i = blockIdx.x*256 + threadIdx.x;
  if (i < n) p[i] = 0;
}

// ---------------- merged CSR build (big + meta graphs) ----------------
__global__ __launch_bounds__(256) void k_hist2(
    const int* __restrict__ dstB, const int* __restrict__ dstM,
    int* __restrict__ degB, int* __restrict__ degM, int E, int ME, int nbE){
  int b = blockIdx.x, t = threadIdx.x;
  if (b < nbE){ int i = b*256+t; if (i < E) atomicAdd(&degB[dstB[i]], 1); }
  else { int i = (b-nbE)*256+t; if (i < ME) atomicAdd(&degM[dstM[i]], 1); }
}

__global__ __launch_bounds__(256) void k_scan1b(
    const int* __restrict__ degB, int* __restrict__ rpB, int* __restrict__ bsB,
    int nB, int nbB,
    const int* __restrict__ degM, int* __restrict__ rpM, int* __restrict__ bsM,
    int nM){
  __shared__ int ls[256];
  int blk = blockIdx.x, t = threadIdx.x;
  const int* deg; int* rowptr; int* bsum; int n; int b;
  if (blk < nbB){ deg=degB; rowptr=rpB; bsum=bsB; n=nB; b=blk; }
  else          { deg=degM; rowptr=rpM; bsum=bsM; n=nM; b=blk-nbB; }
  int base = b*1024 + t*4;
  int v0 = (base+0<n)?deg[base+0]:0;
  int v1 = (base+1<n)?deg[base+1]:0;
  int v2 = (base+2<n)?deg[base+2]:0;
  int v3 = (base+3<n)?deg[base+3]:0;
  int tsum = v0+v1+v2+v3;
  ls[t] = tsum; __syncthreads();
  for (int o=1;o<256;o<<=1){
    int x = (t>=o) ? ls[t-o] : 0;
    __syncthreads();
    ls[t] += x;
    __syncthreads();
  }
  int excl = ls[t]-tsum;
  if (t==255) bsum[b] = ls[255];
  if (base+0<n) rowptr[base+0]=excl;
  if (base+1<n) rowptr[base+1]=excl+v0;
  if (base+2<n) rowptr[base+2]=excl+v0+v1;
  if (base+3<n) rowptr[base+3]=excl+v0+v1+v2;
}

// scan3 with in-block prefix of block sums (scan2 merged in).
__global__ __launch_bounds__(256) void k_scan3b(
    int* __restrict__ rpB, const int* __restrict__ bsB, int* __restrict__ curB,
    int nB, int nb3B, int nbsB,
    int* __restrict__ rpM, const int* __restrict__ bsM, int* __restrict__ curM,
    int nM, int nbsM){
  __shared__ int spre;
  int blk = blockIdx.x, t = threadIdx.x;
  if (blk < nb3B){
    if (t == 0){
      int chunk = blk >> 2;
      int pre = 0;
      for (int j=0;j<chunk;j++) pre += bsB[j];
      spre = pre;
      if (blk == 0){
        int tot = 0;
        for (int j=0;j<nbsB;j++) tot += bsB[j];
        rpB[nB] = tot;
      }
    }
    __syncthreads();
    int i = blk*256 + t;
    if (i < nB){ int r = rpB[i] + spre; rpB[i] = r; curB[i] = r; }
  } else {
    int b2 = blk - nb3B;
    if (t == 0){
      int chunk = b2 >> 2;
      int pre = 0;
      for (int j=0;j<chunk;j++) pre += bsM[j];
      spre = pre;
      if (b2 == 0){
        int tot = 0;
        for (int j=0;j<nbsM;j++) tot += bsM[j];
        rpM[nM] = tot;
      }
    }
    __syncthreads();
    int i = b2*256 + t;
    if (i < nM){ int r = rpM[i] + spre; rpM[i] = r; curM[i] = r; }
  }
}

// scatter. Big graph: pack (src | meid<<17) into one int.
__global__ __launch_bounds__(256) void k_scatter2(
    const int* __restrict__ dstB, const int* __restrict__ srcB,
    const int* __restrict__ auxB, int* __restrict__ curB,
    int* __restrict__ epackB, int E, int nbE,
    const int* __restrict__ dstM, const int* __restrict__ srcM,
    int* __restrict__ curM, int* __restrict__ esrcM, int* __restrict__ eauxM,
    int ME){
  int blk = blockIdx.x, t = threadIdx.x;
  if (blk < nbE){
    int e = blk*256 + t;
    if (e < E){
      int p = atomicAdd(&curB[dstB[e]], 1);
      epackB[p] = srcB[e] | (auxB[e] << 17);
    }
  } else {
    int e = (blk-nbE)*256 + t;
    if (e < ME){
      int p = atomicAdd(&curM[dstM[e]], 1);
      esrcM[p] = srcM[e];
      eauxM[p] = e;
    }
  }
}

// ---------------- meta-graph edges: CSR, atomic-free, writes mef ----------------
// agg written PRE-NORMALIZED (softmax denominator folded in here).
__global__ __launch_bounds__(256) void edge_meta_csr(
    const int* __restrict__ rowptr, const int* __restrict__ esrc,
    const int* __restrict__ eorig,
    const unsigned short* __restrict__ qm, const unsigned short* __restrict__ kfm,
    const unsigned short* __restrict__ vm,
    const float* __restrict__ base, unsigned short* __restrict__ mef,
    float* __restrict__ agg, int NM)
{
  int d = blockIdx.x*4 + (threadIdx.x>>6);
  if (d >= NM) return;
  int lane = threadIdx.x & 63;
  const float* be2 = base+152; const float* be1 = base+16; const float* bn1 = base+8;
  size_t dq = (size_t)d*DD;
  float q0 = b2f(qm[dq+lane]), q1 = b2f(qm[dq+64+lane]);
  float w0 = be2[lane], w1 = be2[64+lane];
  int h0 = lane>>4, h1 = h0+4;
  float bias0 = be1[h0] + bn1[h0];
  float bias1 = be1[h1] + bn1[h1];
  float z0=0.f, z1=0.f, a0=0.f, a1=0.f;
  int i0 = rowptr[d], i1 = rowptr[d+1];
  for (int i=i0; i<i1; i++){
    int s = esrc[i], e = eorig[i];
    size_t so=(size_t)s*DD, eo=(size_t)e*DD;
    float ke0 = b2f(kfm[so+lane])    * w0;
    float ke1 = b2f(kfm[so+64+lane]) * w1;
    mef[eo+lane]=f2b(ke0); mef[eo+64+lane]=f2b(ke1);
    float p0 = q0*ke0, p1 = q1*ke1;
#pragma unroll
    for (int m=1;m<16;m<<=1){ p0 += __shfl_xor(p0,m,64); p1 += __shfl_xor(p1,m,64); }
    float e0 = __expf(p0*0.25f + bias0);
    float e1 = __expf(p1*0.25f + bias1);
    z0 += e0; z1 += e1;
    a0 += e0*b2f(vm[so+lane]);
    a1 += e1*b2f(vm[so+64+lane]);
  }
  float inv0 = 1.f/(z0 + 1e-9f);
  float inv1 = 1.f/(z1 + 1e-9f);
  agg[dq+lane]    = a0*inv0;
  agg[dq+64+lane] = a1*inv1;
}

// Fused meta-learner over [meta_out (Ma rows, f32) | mef (bf16)] — wide launch.
__global__ __launch_bounds__(128) void learner2(
    const float* __restrict__ Xa, const unsigned short* __restrict__ Xb, int Ma,
    const void* __restrict__ u, const void* __restrict__ W2,
    const void* __restrict__ W1,
    float* __restrict__ p2a, float* __restrict__ p1a,
    unsigned short* __restrict__ w2me, unsigned short* __restrict__ p1b,
    const float* __restrict__ base, const int* __restrict__ dflag)
{
  __shared__ float sX[128];
  __shared__ float st[16];
  __shared__ float sw[16];
  const bool wf32 = (*dflag) != 0;
  const int blk = blockIdx.x, t = threadIdx.x;
  const bool isB = (blk >= Ma);
  const int m = isB ? (blk - Ma) : blk;
  if (isB) sX[t] = b2f(Xb[(size_t)m*DD + t]);
  else     sX[t] = Xa[(size_t)m*DD + t];
  __syncthreads();
  int l = t>>3, j = t&7;
  float part = 0.f;
  for (int d=j*16; d<j*16+16; d++) part += sX[d]*gld(u, l*128+d, wf32);
  part += __shfl_xor(part,1,64); part += __shfl_xor(part,2,64); part += __shfl_xor(part,4,64);
  if (j==0) st[l] = part * 0.08838834764831845f;
  __syncthreads();
  float mx=-1e30f;
  for (int i=0;i<16;i++) mx = fmaxf(mx, st[i]);
  float ssum=0.f;
  for (int i=0;i<16;i++) ssum += __expf(st[i]-mx);
  float inv = 1.f/ssum;
  if (t<16) sw[t] = __expf(st[t]-mx)*inv;
  __syncthreads();
  float a=0.f;
  for (int i=0;i<16;i++) a += sw[i]*gld(W2, i*128+t, wf32);
  if (isB) w2me[(size_t)m*DD+t] = f2b(base[152+t] + a);
  else     p2a[(size_t)m*DD+t] = a;
  if (t<8){
    float bb=0.f;
    for (int i=0;i<16;i++) bb += sw[i]*gld(W1, i*8+t, wf32);
    if (isB) p1b[(size_t)m*HH+t] = f2b(bb);
    else     p1a[(size_t)m*HH+t] = bb;
  }
}

// ---------------- big-graph: fused scores+agg, fp8 kv, packed indices ----------
// Packed-f32 math; agg written PRE-NORMALIZED (0.125 fp8 v-descale folded into
// the 1/z normalization, no z round-trip).
__global__ __launch_bounds__(256) void edge_fused(
    const int* __restrict__ rowptr, const int* __restrict__ epack,
    const int* __restrict__ mnid,
    const unsigned short* __restrict__ q, const unsigned char* __restrict__ kv8,
    const unsigned short* __restrict__ w2me, const unsigned short* __restrict__ p1me,
    const float* __restrict__ p1mn, const float* __restrict__ base,
    unsigned short* __restrict__ aggb, int N)
{
  int wv = blockIdx.x*4 + (threadIdx.x>>6);
  int d0 = wv*4;
  if (d0 >= N) return;
  int lane = threadIdx.x & 63;
  int grp = lane >> 4, l16 = lane & 15;
  int c8 = l16 * 8;
  int h = l16 >> 1;
  const float biash0 = base[16+h] + base[8+h];

  const int nd = (N - d0 < 4) ? (N - d0) : 4;
  int rp[5];
#pragma unroll
  for (int j=0;j<5;j++){ int ix = d0 + j; if (ix > N) ix = N; rp[j] = rowptr[ix]; }
  float bias[4];
#pragma unroll
  for (int j=0;j<4;j++){
    int ix = d0 + j; if (ix > N-1) ix = N-1;
    bias[j] = biash0 + p1mn[(size_t)mnid[ix]*HH + h];
  }

  uint4 qraw = *(const uint4*)(q + (size_t)d0*DD + c8);
  for (int dd=0; dd<nd; dd++){
    int d = d0 + dd;
    size_t dq = (size_t)d*DD;
    uint4 qcur = qraw;
    if (dd+1 < nd) qraw = *(const uint4*)(q + (size_t)(d+1)*DD + c8);
    f32x2 qv[4];
    {
      const unsigned int* qw = (const unsigned int*)&qcur;
#pragma unroll
      for (int j=0;j<4;j++) qv[j] = bfpair(qw[j]) * 0.03125f;  // 0.25 * 1/8 (k fp8 scale)
    }
    const float biasd = bias[dd];

    float zh = 0.f;
    f32x2 a2[4];
#pragma unroll
    for (int j=0;j<4;j++) a2[j] = (f32x2){0.f,0.f};

    int i0 = rp[dd], i1 = rp[dd+1];
    int i = i0 + grp;
    for (; i + 4 < i1; i += 8){
      unsigned int v0p = (unsigned int)epack[i];
      unsigned int v1p = (unsigned int)epack[i+4];
      int s0 = v0p & 0x1FFFF, me0 = v0p >> 17;
      int s1 = v1p & 0x1FFFF, me1 = v1p >> 17;
      size_t kvo0 = (size_t)s0*256, mo0 = (size_t)me0*DD;
      size_t kvo1 = (size_t)s1*256, mo1 = (size_t)me1*DD;
      uint2 kraw0 = *(const uint2*)(kv8 + kvo0 + c8);
      uint2 vraw0 = *(const uint2*)(kv8 + kvo0 + 128 + c8);
      uint4 wraw0 = *(const uint4*)(w2me + mo0 + c8);
      float pm0 = b2f(p1me[(size_t)me0*HH + h]);
      uint2 kraw1 = *(const uint2*)(kv8 + kvo1 + c8);
      uint2 vraw1 = *(const uint2*)(kv8 + kvo1 + 128 + c8);
      uint4 wraw1 = *(const uint4*)(w2me + mo1 + c8);
      float pm1 = b2f(p1me[(size_t)me1*HH + h]);
      f32x2 k0f[4], v0f[4], k1f[4], v1f[4];
      cvt8(kraw0, k0f); cvt8(vraw0, v0f);
      cvt8(kraw1, k1f); cvt8(vraw1, v1f);
      const unsigned int* ww0 = (const unsigned int*)&wraw0;
      const unsigned int* ww1 = (const unsigned int*)&wraw1;
      f32x2 pA2 = (f32x2){0.f,0.f}, pB2 = (f32x2){0.f,0.f};
#pragma unroll
      for (int j=0;j<4;j++){
        pA2 += qv[j] * (k0f[j] * bfpair(ww0[j]));
        pB2 += qv[j] * (k1f[j] * bfpair(ww1[j]));
      }
      float pA = pA2[0] + pA2[1];
      float pB = pB2[0] + pB2[1];
      pA += __shfl_xor(pA, 1, 64);
      pB += __shfl_xor(pB, 1, 64);
      float ex0 = __expf(pA + biasd + pm0);
      float ex1 = __expf(pB + biasd + pm1);
      zh += ex0 + ex1;
#pragma unroll
      for (int j=0;j<4;j++) a2[j] += v0f[j]*ex0 + v1f[j]*ex1;
    }
    if (i < i1){
      unsigned int vp = (unsigned int)epack[i];
      int s = vp & 0x1FFFF, me = vp >> 17;
      size_t kvo = (size_t)s*256, mo = (size_t)me*DD;
      uint2 kraw = *(const uint2*)(kv8 + kvo + c8);
      uint2 vraw = *(const uint2*)(kv8 + kvo + 128 + c8);
      uint4 wraw = *(const uint4*)(w2me + mo + c8);
      float pm = b2f(p1me[(size_t)me*HH + h]);
      f32x2 kf[4], vf[4];
      cvt8(kraw, kf); cvt8(vraw, vf);
      const unsigned int* ww = (const unsigned int*)&wraw;
      f32x2 p2 = (f32x2){0.f,0.f};
#pragma unroll
      for (int j=0;j<4;j++) p2 += qv[j] * (kf[j] * bfpair(ww[j]));
      float p = p2[0] + p2[1];
      p += __shfl_xor(p, 1, 64);
      float ex = __expf(p + biasd + pm);
      zh += ex;
#pragma unroll
      for (int j=0;j<4;j++) a2[j] += vf[j]*ex;
    }

    zh += __shfl_xor(zh, 16, 64); zh += __shfl_xor(zh, 32, 64);
    float r[8];
#pragma unroll
    for (int j=0;j<4;j++){
      float v0 = a2[j][0], v1 = a2[j][1];
      v0 += __shfl_xor(v0, 16, 64); v0 += __shfl_xor(v0, 32, 64);
      v1 += __shfl_xor(v1, 16, 64); v1 += __shfl_xor(v1, 32, 64);
      r[2*j] = v0; r[2*j+1] = v1;
    }
    if (grp == 0){
      float inv = 0.125f / (zh + 1e-9f);   // fp8 v-descale folded into 1/z
      us4 o0, o1;
      o0.x=f2b(r[0]*inv); o0.y=f2b(r[1]*inv); o0.z=f2b(r[2]*inv); o0.w=f2b(r[3]*inv);
      o1.x=f2b(r[4]*inv); o1.y=f2b(r[5]*inv); o1.z=f2b(r[6]*inv); o1.w=f2b(r[7]*inv);
      *(us4*)(aggb + dq + c8)     = o0;
      *(us4*)(aggb + dq + c8 + 4) = o1;
    }
  }
}

// One 16-lane group per target; vectorized feat row read + shuffle reduce.
__global__ __launch_bounds__(256) void readout(
    const int* __restrict__ tgt, const int* __restrict__ mnid,
    const unsigned short* __restrict__ featb, const float* __restrict__ p1mn,
    const float* __restrict__ base, float* __restrict__ acc,
    void* __restrict__ out, int last, float invNB, int BT,
    const int* __restrict__ dflag)
{
  int t = blockIdx.x*256 + threadIdx.x;
  int ti = t >> 4, l16 = t & 15;
  if (ti >= BT) return;
  int idx = tgt[ti]; int mn = mnid[idx];
  int h = l16 >> 1;
  float tw = base[h] + p1mn[(size_t)mn*HH + h];
  uint4 raw = *(const uint4*)(featb + (size_t)idx*DD + l16*8);
  const unsigned short* hw = (const unsigned short*)&raw;
  float s = 0.f;
#pragma unroll
  for (int j=0;j<8;j++) s += b2f(hw[j]);
  float part = tw * s;
  part += __shfl_xor(part, 1, 64);
  part += __shfl_xor(part, 2, 64);
  part += __shfl_xor(part, 4, 64);
  part += __shfl_xor(part, 8, 64);
  if (l16 == 0){
    if (!last) acc[ti] = part;
    else {
      float r = (acc[ti] + part) * invNB;
      if ((*dflag) != 0) ((float*)out)[ti] = r;
      else ((__hip_bfloat16*)out)[ti] = __float2bfloat16(r);
    }
  }
}

extern "C" void kernel_launch(void* const* d_in, const int* in_sizes, int n_in,
                              void* d_out, int out_size, void* d_ws, size_t ws_size,
                              hipStream_t stream) {
  const void* emb   = d_in[0];
  const void* u     = d_in[1];
  const void* W2lat = d_in[2];
  const void* W1lat = d_in[3];
  WPtrs wptrs;
  for (int i=0;i<8;i++) wptrs.p[i] = d_in[4+i];
  const int* node_vals      = (const int*)d_in[12];
  const int* meta_node_vals = (const int*)d_in[13];
  const int* src            = (const int*)d_in[14];
  const int* dst            = (const int*)d_in[15];
  const int* meta_src       = (const int*)d_in[16];
  const int* meta_dst       = (const int*)d_in[17];
  const int* meta_node_id   = (const int*)d_in[18];
  const int* meta_edge_id   = (const int*)d_in[19];
  const int* target_idx     = (const int*)d_in[20];
  const int* static_vals    = (const int*)d_in[21];
  const int* static_src     = (const int*)d_in[22];
  const int* static_dst     = (const int*)d_in[23];

  const int N  = in_sizes[12];
  const int MN = in_sizes[13];
  const int E  = in_sizes[14];
  const int ME = in_sizes[16];
  const int BT = in_sizes[20];
  const int NSRC = in_sizes[22];
  const int NB = in_sizes[8] / (DD*DD);

  float* ws = (float*)d_ws;
  size_t off = 0;
  // keep every allocation 16B-aligned (global_load_lds sources need it)
  auto allocf = [&](size_t n){ float* p = ws + off; off += (n + 3) & ~(size_t)3; return p; };
  auto allocb = [&](size_t n){ unsigned short* p = (unsigned short*)(ws + off); off += (((n+1)/2) + 3) & ~(size_t)3; return p; };
  auto alloci = [&](size_t n){ int* p = (int*)(ws + off); off += (n + 3) & ~(size_t)3; return p; };
  int*            dflag = (int*)ws; off += 4;
  unsigned short* feat  = allocb((size_t)N*DD);
  unsigned short* q     = allocb((size_t)N*DD);
  unsigned char*  kv8   = (unsigned char*)allocf((size_t)N*64);  // N x 256B fp8 rows
  unsigned short* aggb  = allocb((size_t)N*DD);
  float*          meta_feat= allocf((size_t)MN*DD);
  float*          agg_m = allocf((size_t)MN*DD);
  unsigned short* q_m   = allocb((size_t)MN*DD);
  unsigned short* kf_m  = allocb((size_t)MN*DD);
  unsigned short* v_m   = allocb((size_t)MN*DD);
  float*          meta_out = allocf((size_t)MN*DD);
  unsigned short* mef   = allocb((size_t)ME*DD);
  float*          p2mn  = allocf((size_t)MN*DD);
  float*          p1mn  = allocf((size_t)MN*HH);
  unsigned short* w2me  = allocb((size_t)ME*DD);
  unsigned short* p1me  = allocb((size_t)ME*HH);
  float*          base  = allocf(280);
  float*          acc   = allocf((size_t)BT);
  unsigned short* wstage= allocb((size_t)8*NB*DD*DD);
  int*            rowptr= alloci((size_t)N+1);
  int*            cursor= alloci((size_t)N);
  int*            epack = alloci((size_t)E);
  int*            rowptr_m= alloci((size_t)MN+1);
  int*            cursor_m= alloci((size_t)MN);
  int*            esrc_m  = alloci((size_t)ME);
  int*            eorig_m = alloci((size_t)ME);
  int*            degAll  = alloci((size_t)(N+MN));
  int*            deg     = degAll;
  int*            deg_m   = degAll + N;
  const int nb_scan   = (N + 1023)/1024;
  const int nb_scan_m = (MN + 1023)/1024;
  int*            bsum   = alloci((size_t)nb_scan);
  int*            bsum_m = alloci((size_t)nb_scan_m);
  (void)ws_size; (void)n_in; (void)out_size;

  const float* base_n2 = base + 24;

  k_static<<<1,256,0,stream>>>(emb, static_vals, static_src, static_dst,
                               u, W2lat, W1lat, base, NSRC, dflag);
  gather_rows2<<<((N+MN)*16+255)/256,256,0,stream>>>(emb, node_vals, feat, N,
      meta_node_vals, meta_feat, MN, dflag);

  const int nbE  = (E+255)/256, nbME = (ME+255)/256;
  const int nb3B = (N+255)/256, nb3M = (MN+255)/256;
  zeroi<<<(N+MN+255)/256,256,0,stream>>>(degAll, N+MN);
  k_hist2<<<nbE+nbME,256,0,stream>>>(dst, meta_dst, deg, deg_m, E, ME, nbE);
  k_scan1b<<<nb_scan+nb_scan_m,256,0,stream>>>(deg, rowptr, bsum, N, nb_scan,
      deg_m, rowptr_m, bsum_m, MN);
  k_scan3b<<<nb3B+nb3M,256,0,stream>>>(rowptr, bsum, cursor, N, nb3B, nb_scan,
      rowptr_m, bsum_m, cursor_m, MN, nb_scan_m);
  k_scatter2<<<nbE+nbME,256,0,stream>>>(dst, src, meta_edge_id, cursor,
      epack, E, nbE, meta_dst, meta_src, cursor_m, esrc_m, eorig_m, ME);

  w_repack16<<<8*NB*64,256,0,stream>>>(wptrs, wstage, NB, dflag);

  const int gm = (MN+63)/64;
  const int gN = (N+63)/64;
  const float invNB = 1.0f/(float)NB;

  for (int b=0;b<NB;b++){
    const unsigned short* wq_m = wstage + (size_t)(0*NB+b)*DD*DD;
    const unsigned short* wk_m = wstage + (size_t)(1*NB+b)*DD*DD;
    const unsigned short* wv_m = wstage + (size_t)(2*NB+b)*DD*DD;
    const unsigned short* wo_m = wstage + (size_t)(3*NB+b)*DD*DD;
    const unsigned short* wqb  = wstage + (size_t)(4*NB+b)*DD*DD;
    const unsigned short* wkb  = wstage + (size_t)(5*NB+b)*DD*DD;
    const unsigned short* wvb  = wstage + (size_t)(6*NB+b)*DD*DD;
    const unsigned short* wob  = wstage + (size_t)(7*NB+b)*DD*DD;

    // ---- meta conv (CSR, atomic-free) ----
    gemm_qkv<EPI_SCALE_CONST,false,false><<<gm,256,0,stream>>>(meta_feat,
        wq_m, wk_m, wv_m, q_m, kf_m, DD, v_m, DD, MN, base_n2, nullptr, nullptr);
    edge_meta_csr<<<(MN+3)/4,256,0,stream>>>(rowptr_m, esrc_m, eorig_m,
        q_m, kf_m, v_m, base, mef, agg_m, MN);
    // meta Wo: meta_out = relu(agg_m@Wo) (f32, agg pre-normalized); meta_feat += relu
    gemm128m<EPI_RELU_RES2,false,false><<<gm,256,0,stream>>>(agg_m, wo_m,
        meta_out, MN, nullptr, meta_feat, meta_feat);
    // wide fused learners: MN rows (f32 meta_out) + ME rows (bf16 mef)
    learner2<<<MN+ME,128,0,stream>>>(meta_out, mef, MN, u, W2lat, W1lat,
        p2mn, p1mn, w2me, p1me, base, dflag);

    // ---- big conv (fp8 kv) ----
    gemm_qkv<EPI_SCALE_GATHER,true,true><<<gN,256,0,stream>>>(feat, wqb, wkb, wvb,
        q, kv8, 0, kv8 + 128, 0, N, base_n2, p2mn, meta_node_id);
    edge_fused<<<(N+15)/16,256,0,stream>>>(rowptr, epack,
        meta_node_id, q, kv8, w2me, p1me, p1mn, base, aggb, N);
    gemm128m<EPI_RELU_RES,true,true><<<gN,256,0,stream>>>(aggb, wob, feat, N,
        feat, nullptr, nullptr);

    // ---- readout ----
    readout<<<(BT*16+255)/256,256,0,stream>>>(target_idx, meta_node_id, feat, p1mn,
        base, acc, d_out, (b==NB-1) ? 1 : 0, invNB, BT, dflag);
  }
}

// Round 2
// 647.932 us; speedup vs baseline: 1.0757x; 1.0396x over previous
//
#include <hip/hip_runtime.h>
#include <hip/hip_bf16.h>
#include <hip/hip_fp8.h>

#define DD   128
#define HH   8

typedef short bf16x8 __attribute__((ext_vector_type(8)));
typedef float f32x4  __attribute__((ext_vector_type(4)));
typedef float f32x2  __attribute__((ext_vector_type(2)));

__device__ __forceinline__ float b2f(unsigned short v){
  union { unsigned int u; float f; } x; x.u = ((unsigned int)v) << 16; return x.f;
}
__device__ __forceinline__ unsigned short f2b(float f){
  __hip_bfloat16 h = __float2bfloat16(f);
  return *(unsigned short*)&h;
}
__device__ __forceinline__ unsigned char f2f8(float x){
  __hip_fp8_e4m3 h(x);
  return h.__x;
}
__device__ __forceinline__ float f82f(unsigned char b){
  __hip_fp8_e4m3 h; h.__x = b;
  return (float)h;
}
// 4 fp8 bytes (one u32) -> 4 floats; HW packed cvt when available.
__device__ __forceinline__ void cvt4(unsigned int w, float* o){
#if defined(__has_builtin)
# if __has_builtin(__builtin_amdgcn_cvt_pk_f32_fp8)
  f32x2 lo = __builtin_amdgcn_cvt_pk_f32_fp8((int)w, false);
  f32x2 hi = __builtin_amdgcn_cvt_pk_f32_fp8((int)w, true);
  o[0]=lo[0]; o[1]=lo[1]; o[2]=hi[0]; o[3]=hi[1];
  return;
# endif
#endif
  o[0]=f82f(w&0xff); o[1]=f82f((w>>8)&0xff);
  o[2]=f82f((w>>16)&0xff); o[3]=f82f((w>>24)&0xff);
}
struct __align__(8) us4 { unsigned short x,y,z,w; };
struct __align__(16) us8 { unsigned short s[8]; };

__device__ __forceinline__ float gld(const void* p, size_t i, bool f32){
  if (f32) return ((const float*)p)[i];
  return b2f(((const unsigned short*)p)[i]);
}

// async global->LDS, 16B per lane (wave-uniform LDS base + lane*16)
__device__ __forceinline__ void gll16(const void* g, void* l){
  __builtin_amdgcn_global_load_lds(
      (const __attribute__((address_space(1))) unsigned int*)g,
      (__attribute__((address_space(3))) unsigned int*)l, 16, 0, 0);
}

// ALL weight blocks (8 tensors x NB matrices) -> bf16 TRANSPOSED staging, one launch.
struct WPtrs { const void* p[8]; };
__global__ __launch_bounds__(256) void w_repack16(
    WPtrs W, unsigned short* __restrict__ stage, int NBt,
    const int* __restrict__ dflag)
{
  const bool wf32 = (*dflag) != 0;
  int idx = blockIdx.x >> 6;
  int ti = idx / NBt, bi = idx - ti*NBt;
  size_t bo = (size_t)bi*DD*DD;
  int i = (blockIdx.x & 63)*256 + threadIdx.x;
  int k = i >> 7, n = i & 127;
  float x;
  if (wf32) x = ((const float*)W.p[ti])[bo + i];
  else      x = b2f(((const unsigned short*)W.p[ti])[bo + i]);
  stage[(size_t)idx*DD*DD + n*DD + k] = f2b(x);
}

enum { EPI_STORE=0, EPI_SCALE_CONST=1, EPI_SCALE_GATHER=2, EPI_RELU=3,
       EPI_RELU_RES=4, EPI_RELU_RES2=5 };

#define CPAD 132

// ===== shared GEMM building blocks: linear LDS + XOR chunk swizzle =====
// LDS layout: row r (128 bf16 = 256B = 16 chunks of 16B); logical chunk c is
// stored at chunk c ^ (r&7).  Written either by global_load_lds with the
// inverse-swizzled per-lane GLOBAL address (linear LDS dest), or by ds_write
// at the swizzled offset.  Fragment reads use offset  kk ^ ((am&7)<<3).

// C[M,128] = epi( A[M,128] @ B[128,128] ), B bf16 TRANSPOSED ([n][k]).
// EPI_RELU_RES : C = relu(x) + Rb(bf16)                  [big Wo, OUTB=1]
// EPI_RELU_RES2: Cv = relu(x) f32; C2 = relu(x)+Rf (f32) [meta Wo, OUTB=0]
template<int EPI, bool INB, bool OUTB>
__global__ __launch_bounds__(256) void gemm128m(
    const void* __restrict__ Av, const unsigned short* __restrict__ Bt,
    void* __restrict__ Cv, int M,
    const unsigned short* __restrict__ Rb,
    const float* __restrict__ Rf, float* __restrict__ C2)
{
  __shared__ __align__(16) unsigned short Asb[64*128];
  __shared__ __align__(16) unsigned short Btb[16896];  // B: 32KB / C: 64x132 f32
  const int tid = threadIdx.x;
  const int wave = tid >> 6, lane = tid & 63;
  const int row0 = blockIdx.x * 64;

  if (INB){
    const char* Ab = (const char*)Av;
    int n4 = lane >> 4, c = lane & 15;
#pragma unroll
    for (int op=0; op<4; op++){
      int rA = wave*16 + op*4;
      int n = rA + n4;
      int gr = row0 + n; if (gr >= M) gr = M - 1;
      gll16(Ab + (size_t)gr*256 + ((size_t)((c ^ (n & 7)) << 4)), &Asb[rA*128]);
    }
  } else {
    const float* Af = (const float*)Av;
    int r = tid >> 2, cb = (tid & 3) * 32, rx = (r & 7) << 3;
    int gr = row0 + r;
#pragma unroll
    for (int j=0;j<8;j++){
      int cc = cb + j*4;
      float4 val = make_float4(0.f,0.f,0.f,0.f);
      if (gr < M) val = *(const float4*)(Af + (size_t)gr*DD + cc);
      us4 o; o.x=f2b(val.x); o.y=f2b(val.y); o.z=f2b(val.z); o.w=f2b(val.w);
      *(us4*)&Asb[r*128 + (cc ^ rx)] = o;
    }
  }
  {
    int n4 = lane >> 4, c = lane & 15;
#pragma unroll
    for (int op=0; op<8; op++){
      int rB = wave*32 + op*4;
      int n = rB + n4;
      gll16((const char*)Bt + (size_t)n*256 + ((size_t)((c ^ (n & 7)) << 4)),
            &Btb[rB*128]);
    }
  }
  __syncthreads();

  f32x4 acc[8];
#pragma unroll
  for (int t=0;t<8;t++) acc[t] = (f32x4){0.f,0.f,0.f,0.f};
  const int am = (lane & 15), kq = (lane >> 4) * 8, axr = (am & 7) << 3;
#pragma unroll
  for (int k0=0;k0<128;k0+=32){
    int xo = (k0 + kq) ^ axr;
    bf16x8 a = *(bf16x8*)&Asb[(wave*16 + am)*128 + xo];
#pragma unroll
    for (int t=0;t<8;t++){
      bf16x8 b = *(bf16x8*)&Btb[(t*16 + am)*128 + xo];
      acc[t] = __builtin_amdgcn_mfma_f32_16x16x32_bf16(a, b, acc[t], 0,0,0);
    }
  }
  __syncthreads();
  float* Cls = (float*)Btb;
  {
    int rr = wave*16 + (lane>>4)*4;
    int cc = lane & 15;
#pragma unroll
    for (int t=0;t<8;t++)
#pragma unroll
      for (int r=0;r<4;r++)
        Cls[(rr + r)*CPAD + t*16 + cc] = acc[t][r];
  }
  __syncthreads();

  {
    int r = tid >> 2, cb = (tid & 3) * 32;
    int gr = row0 + r;
    if (gr < M){
#pragma unroll
      for (int j=0;j<8;j++){
        int c = cb + j*4;
        float4 o = *(float4*)&Cls[r*CPAD + c];
        if (EPI == EPI_RELU_RES){
          us4 rb = *(const us4*)(Rb + (size_t)gr*DD + c);
          o.x=fmaxf(o.x,0.f)+b2f(rb.x); o.y=fmaxf(o.y,0.f)+b2f(rb.y);
          o.z=fmaxf(o.z,0.f)+b2f(rb.z); o.w=fmaxf(o.w,0.f)+b2f(rb.w);
        } else if (EPI == EPI_RELU_RES2){
          o.x=fmaxf(o.x,0.f); o.y=fmaxf(o.y,0.f); o.z=fmaxf(o.z,0.f); o.w=fmaxf(o.w,0.f);
          float4 rf = *(const float4*)(Rf + (size_t)gr*DD + c);
          *(float4*)(C2 + (size_t)gr*DD + c) =
              make_float4(o.x+rf.x, o.y+rf.y, o.z+rf.z, o.w+rf.w);
        }
        if (OUTB){
          us4 ob; ob.x=f2b(o.x); ob.y=f2b(o.y); ob.z=f2b(o.z); ob.w=f2b(o.w);
          *(us4*)((unsigned short*)Cv + (size_t)gr*DD + c) = ob;
        } else {
          *(float4*)((float*)Cv + (size_t)gr*DD + c) = o;
        }
      }
    }
  }
}

// Fused Q/K/V gemm. FP8KV: phases 1/2 write fp8 (x8 scale) into 256B/row kv buffer.
template<int EPIQ, bool INB, bool FP8KV>
__global__ __launch_bounds__(256) void gemm_qkv(
    const void* __restrict__ Av,
    const unsigned short* __restrict__ Btq, const unsigned short* __restrict__ Btk,
    const unsigned short* __restrict__ Btv,
    void* __restrict__ Cq, void* __restrict__ Ck, int stK,
    void* __restrict__ Cvo, int stV, int M,
    const float* __restrict__ svec, const float* __restrict__ P2,
    const int* __restrict__ gidx)
{
  __shared__ __align__(16) unsigned short Asb[64*128];
  __shared__ __align__(16) unsigned short Btb[16896];
  const int tid = threadIdx.x;
  const int wave = tid >> 6, lane = tid & 63;
  const int row0 = blockIdx.x * 64;

  if (INB){
    const char* Ab = (const char*)Av;
    int n4 = lane >> 4, c = lane & 15;
#pragma unroll
    for (int op=0; op<4; op++){
      int rA = wave*16 + op*4;
      int n = rA + n4;
      int gr = row0 + n; if (gr >= M) gr = M - 1;
      gll16(Ab + (size_t)gr*256 + ((size_t)((c ^ (n & 7)) << 4)), &Asb[rA*128]);
    }
  } else {
    const float* Af = (const float*)Av;
    int r = tid >> 2, cb = (tid & 3) * 32, rx = (r & 7) << 3;
    int gr = row0 + r;
#pragma unroll
    for (int j=0;j<8;j++){
      int cc = cb + j*4;
      float4 val = make_float4(0.f,0.f,0.f,0.f);
      if (gr < M) val = *(const float4*)(Af + (size_t)gr*DD + cc);
      us4 o; o.x=f2b(val.x); o.y=f2b(val.y); o.z=f2b(val.z); o.w=f2b(val.w);
      *(us4*)&Asb[r*128 + (cc ^ rx)] = o;
    }
  }

  const unsigned short* Bts[3] = {Btq, Btk, Btv};
  void* Cs[3] = {Cq, Ck, Cvo};
  const int sts[3] = {DD, stK, stV};
  const int am = (lane & 15), kq = (lane >> 4) * 8, axr = (am & 7) << 3;

  for (int ph=0; ph<3; ph++){
    {
      const unsigned short* Bt = Bts[ph];
      int n4 = lane >> 4, c = lane & 15;
#pragma unroll
      for (int op=0; op<8; op++){
        int rB = wave*32 + op*4;
        int n = rB + n4;
        gll16((const char*)Bt + (size_t)n*256 + ((size_t)((c ^ (n & 7)) << 4)),
              &Btb[rB*128]);
      }
    }
    __syncthreads();
    f32x4 acc[8];
#pragma unroll
    for (int t=0;t<8;t++) acc[t] = (f32x4){0.f,0.f,0.f,0.f};
#pragma unroll
    for (int k0=0;k0<128;k0+=32){
      int xo = (k0 + kq) ^ axr;
      bf16x8 a = *(bf16x8*)&Asb[(wave*16 + am)*128 + xo];
#pragma unroll
      for (int t=0;t<8;t++){
        bf16x8 b = *(bf16x8*)&Btb[(t*16 + am)*128 + xo];
        acc[t] = __builtin_amdgcn_mfma_f32_16x16x32_bf16(a, b, acc[t], 0,0,0);
      }
    }
    __syncthreads();
    float* Cls = (float*)Btb;
    {
      int rr = wave*16 + (lane>>4)*4;
      int cc = lane & 15;
#pragma unroll
      for (int t=0;t<8;t++)
#pragma unroll
        for (int r=0;r<4;r++)
          Cls[(rr + r)*CPAD + t*16 + cc] = acc[t][r];
    }
    __syncthreads();
    {
      int r = tid >> 2, cb = (tid & 3) * 32;
      int gr = row0 + r;
      if (gr < M){
#pragma unroll
        for (int j=0;j<8;j++){
          int c = cb + j*4;
          float4 o = *(float4*)&Cls[r*CPAD + c];
          if (ph == 0){
            if (EPIQ == EPI_SCALE_GATHER){
              int g = gidx[gr];
              const float* p = P2 + (size_t)g*DD + c;
              o.x*=(svec[c+0]+p[0]); o.y*=(svec[c+1]+p[1]);
              o.z*=(svec[c+2]+p[2]); o.w*=(svec[c+3]+p[3]);
            } else {
              o.x*=svec[c+0]; o.y*=svec[c+1]; o.z*=svec[c+2]; o.w*=svec[c+3];
            }
          }
          if (FP8KV && ph > 0){
            unsigned char* Cb = (unsigned char*)Cs[ph];
            uchar4 ob;
            ob.x=f2f8(o.x*8.f); ob.y=f2f8(o.y*8.f);
            ob.z=f2f8(o.z*8.f); ob.w=f2f8(o.w*8.f);
            *(uchar4*)(Cb + (size_t)gr*256 + c) = ob;
          } else {
            us4 ob; ob.x=f2b(o.x); ob.y=f2b(o.y); ob.z=f2b(o.z); ob.w=f2b(o.w);
            *(us4*)((unsigned short*)Cs[ph] + (size_t)gr*sts[ph] + c) = ob;
          }
        }
      }
    }
    __syncthreads();
  }
}

// Static param-name graph -> base params.  (k_detect fused in.)
__global__ __launch_bounds__(256) void k_static(
    const void* __restrict__ emb, const int* __restrict__ svals,
    const int* __restrict__ ssrc, const int* __restrict__ sdst,
    const void* __restrict__ u, const void* __restrict__ W2,
    const void* __restrict__ W1, float* __restrict__ base, int nsrc,
    int* __restrict__ dflag)
{
  __shared__ float sagg[15][128];
  __shared__ float ssc[15][16];
  __shared__ float sww[15][16];
  __shared__ int swf;
  const int t = threadIdx.x;
  if (t < 64){
    float m = 0.f;
    for (int i=t; i<128; i+=64){
      float x = fabsf(b2f(((const unsigned short*)emb)[i]));
      if (x < 1e30f) m = fmaxf(m, x);
    }
#pragma unroll
    for (int s=1;s<64;s<<=1) m = fmaxf(m, __shfl_xor(m, s, 64));
    if (t==0){ int f = (m > 1e4f) ? 1 : 0; *dflag = f; swf = f; }
  }
  for (int i=t;i<15*128;i+=256) ((float*)sagg)[i]=0.f;
  __syncthreads();
  const bool wf32 = (swf != 0);
  if (t < 128){
    for (int i=0;i<nsrc;i++){
      int row = sdst[i]; int vr = svals[ssrc[i]];
      sagg[row][t] += gld(emb, (size_t)vr*DD + t, wf32);
    }
  }
  __syncthreads();
  if (t < 240){
    int n = t>>4, l = t&15;
    float a=0.f;
    for (int d=0;d<128;d++) a += sagg[n][d]*gld(u, l*128+d, wf32);
    ssc[n][l] = a * 0.08838834764831845f;
  }
  __syncthreads();
  if (t < 15){
    float mx=-1e30f;
    for (int l=0;l<16;l++) mx = fmaxf(mx, ssc[t][l]);
    float s=0.f;
    for (int l=0;l<16;l++){ float e=__expf(ssc[t][l]-mx); sww[t][l]=e; s+=e; }
    float inv = 1.f/s;
    for (int l=0;l<16;l++) sww[t][l]*=inv;
  }
  __syncthreads();
  if (t < 8){
    float a=0.f,b=0.f,c=0.f;
    for (int l=0;l<16;l++){
      float wv = gld(W1, l*8+t, wf32);
      a += sww[0][l]*wv; b += sww[3][l]*wv; c += sww[9][l]*wv;
    }
    base[t]=a; base[8+t]=b; base[16+t]=c;
  }
  if (t < 128){
    float a=0.f,b=0.f;
    for (int l=0;l<16;l++){
      float wv = gld(W2, l*128+t, wf32);
      a += sww[6][l]*wv; b += sww[12][l]*wv;
    }
    base[24+t]=a; base[152+t]=b;
  }
}

// Merged gather: big graph rows -> bf16 feat; meta rows -> f32 meta_feat.
__global__ __launch_bounds__(256) void gather_rows2(
    const void* __restrict__ emb,
    const int* __restrict__ valsB, unsigned short* __restrict__ featB, int nB,
    const int* __restrict__ valsM, float* __restrict__ featM, int nM,
    const int* __restrict__ dflag)
{
  const bool wf32 = (*dflag) != 0;
  int i = blockIdx.x*256 + threadIdx.x;
  bool big = (i < nB*16);
  int i2 = big ? i : (i - nB*16);
  if (!big && i2 >= nM*16) return;
  int r = i2>>4, c = (i2&15)*8;
  int vr = big ? valsB[r] : valsM[r];
  float vb[8];
  if (wf32){
    float4 f0 = *(const float4*)((const float*)emb + (size_t)vr*DD + c);
    float4 f1 = *(const float4*)((const float*)emb + (size_t)vr*DD + c + 4);
    vb[0]=f0.x; vb[1]=f0.y; vb[2]=f0.z; vb[3]=f0.w;
    vb[4]=f1.x; vb[5]=f1.y; vb[6]=f1.z; vb[7]=f1.w;
  } else {
    uint4 raw = *(const uint4*)((const unsigned short*)emb + (size_t)vr*DD + c);
    const unsigned short* hw = (const unsigned short*)&raw;
#pragma unroll
    for (int j=0;j<8;j++) vb[j] = b2f(hw[j]);
  }
  if (big){
    unsigned short* d = featB + (size_t)r*DD + c;
    us4 o0, o1;
    o0.x=f2b(vb[0]); o0.y=f2b(vb[1]); o0.z=f2b(vb[2]); o0.w=f2b(vb[3]);
    o1.x=f2b(vb[4]); o1.y=f2b(vb[5]); o1.z=f2b(vb[6]); o1.w=f2b(vb[7]);
    *(us4*)d = o0; *(us4*)(d+4) = o1;
  } else {
    float* d = featM + (size_t)r*DD + c;
    *(float4*)d     = make_float4(vb[0],vb[1],vb[2],vb[3]);
    *(float4*)(d+4) = make_float4(vb[4],vb[5],vb[6],vb[7]);
  }
}

__global__ __launch_bounds__(256) void zeroi(int* __restrict__ p, int n){
  int i = blockIdx.x*256 + threadIdx.x;
  if (i < n) p[i] = 0;
}

// ---------------- merged CSR build (big + meta graphs) ----------------
__global__ __launch_bounds__(256) void k_hist2(
    const int* __restrict__ dstB, const int* __restrict__ dstM,
    int* __restrict__ degB, int* __restrict__ degM, int E, int ME, int nbE){
  int b = blockIdx.x, t = threadIdx.x;
  if (b < nbE){ int i = b*256+t; if (i < E) atomicAdd(&degB[dstB[i]], 1); }
  else { int i = (b-nbE)*256+t; if (i < ME) atomicAdd(&degM[dstM[i]], 1); }
}

__global__ __launch_bounds__(256) void k_scan1b(
    const int* __restrict__ degB, int* __restrict__ rpB, int* __restrict__ bsB,
    int nB, int nbB,
    const int* __restrict__ degM, int* __restrict__ rpM, int* __restrict__ bsM,
    int nM){
  __shared__ int ls[256];
  int blk = blockIdx.x, t = threadIdx.x;
  const int* deg; int* rowptr; int* bsum; int n; int b;
  if (blk < nbB){ deg=degB; rowptr=rpB; bsum=bsB; n=nB; b=blk; }
  else          { deg=degM; rowptr=rpM; bsum=bsM; n=nM; b=blk-nbB; }
  int base = b*1024 + t*4;
  int v0 = (base+0<n)?deg[base+0]:0;
  int v1 = (base+1<n)?deg[base+1]:0;
  int v2 = (base+2<n)?deg[base+2]:0;
  int v3 = (base+3<n)?deg[base+3]:0;
  int tsum = v0+v1+v2+v3;
  ls[t] = tsum; __syncthreads();
  for (int o=1;o<256;o<<=1){
    int x = (t>=o) ? ls[t-o] : 0;
    __syncthreads();
    ls[t] += x;
    __syncthreads();
  }
  int excl = ls[t]-tsum;
  if (t==255) bsum[b] = ls[255];
  if (base+0<n) rowptr[base+0]=excl;
  if (base+1<n) rowptr[base+1]=excl+v0;
  if (base+2<n) rowptr[base+2]=excl+v0+v1;
  if (base+3<n) rowptr[base+3]=excl+v0+v1+v2;
}

// scan3 with in-block prefix of block sums (scan2 merged in).
__global__ __launch_bounds__(256) void k_scan3b(
    int* __restrict__ rpB, const int* __restrict__ bsB, int* __restrict__ curB,
    int nB, int nb3B, int nbsB,
    int* __restrict__ rpM, const int* __restrict__ bsM, int* __restrict__ curM,
    int nM, int nbsM){
  __shared__ int spre;
  int blk = blockIdx.x, t = threadIdx.x;
  if (blk < nb3B){
    if (t == 0){
      int chunk = blk >> 2;
      int pre = 0;
      for (int j=0;j<chunk;j++) pre += bsB[j];
      spre = pre;
      if (blk == 0){
        int tot = 0;
        for (int j=0;j<nbsB;j++) tot += bsB[j];
        rpB[nB] = tot;
      }
    }
    __syncthreads();
    int i = blk*256 + t;
    if (i < nB){ int r = rpB[i] + spre; rpB[i] = r; curB[i] = r; }
  } else {
    int b2 = blk - nb3B;
    if (t == 0){
      int chunk = b2 >> 2;
      int pre = 0;
      for (int j=0;j<chunk;j++) pre += bsM[j];
      spre = pre;
      if (b2 == 0){
        int tot = 0;
        for (int j=0;j<nbsM;j++) tot += bsM[j];
        rpM[nM] = tot;
      }
    }
    __syncthreads();
    int i = b2*256 + t;
    if (i < nM){ int r = rpM[i] + spre; rpM[i] = r; curM[i] = r; }
  }
}

// scatter. Big graph: pack (src | meid<<17) into one int.
__global__ __launch_bounds__(256) void k_scatter2(
    const int* __restrict__ dstB, const int* __restrict__ srcB,
    const int* __restrict__ auxB, int* __restrict__ curB,
    int* __restrict__ epackB, int E, int nbE,
    const int* __restrict__ dstM, const int* __restrict__ srcM,
    int* __restrict__ curM, int* __restrict__ esrcM, int* __restrict__ eauxM,
    int ME){
  int blk = blockIdx.x, t = threadIdx.x;
  if (blk < nbE){
    int e = blk*256 + t;
    if (e < E){
      int p = atomicAdd(&curB[dstB[e]], 1);
      epackB[p] = srcB[e] | (auxB[e] << 17);
    }
  } else {
    int e = (blk-nbE)*256 + t;
    if (e < ME){
      int p = atomicAdd(&curM[dstM[e]], 1);
      esrcM[p] = srcM[e];
      eauxM[p] = e;
    }
  }
}

// ---------------- meta-graph edges: CSR, atomic-free, writes mef ----------------
// agg written PRE-NORMALIZED (softmax denominator folded in here).
__global__ __launch_bounds__(256) void edge_meta_csr(
    const int* __restrict__ rowptr, const int* __restrict__ esrc,
    const int* __restrict__ eorig,
    const unsigned short* __restrict__ qm, const unsigned short* __restrict__ kfm,
    const unsigned short* __restrict__ vm,
    const float* __restrict__ base, unsigned short* __restrict__ mef,
    float* __restrict__ agg, int NM)
{
  int d = blockIdx.x*4 + (threadIdx.x>>6);
  if (d >= NM) return;
  int lane = threadIdx.x & 63;
  const float* be2 = base+152; const float* be1 = base+16; const float* bn1 = base+8;
  size_t dq = (size_t)d*DD;
  float q0 = b2f(qm[dq+lane]), q1 = b2f(qm[dq+64+lane]);
  float w0 = be2[lane], w1 = be2[64+lane];
  int h0 = lane>>4, h1 = h0+4;
  float bias0 = be1[h0] + bn1[h0];
  float bias1 = be1[h1] + bn1[h1];
  float z0=0.f, z1=0.f, a0=0.f, a1=0.f;
  int i0 = rowptr[d], i1 = rowptr[d+1];
  for (int i=i0; i<i1; i++){
    int s = esrc[i], e = eorig[i];
    size_t so=(size_t)s*DD, eo=(size_t)e*DD;
    float ke0 = b2f(kfm[so+lane])    * w0;
    float ke1 = b2f(kfm[so+64+lane]) * w1;
    mef[eo+lane]=f2b(ke0); mef[eo+64+lane]=f2b(ke1);
    float p0 = q0*ke0, p1 = q1*ke1;
#pragma unroll
    for (int m=1;m<16;m<<=1){ p0 += __shfl_xor(p0,m,64); p1 += __shfl_xor(p1,m,64); }
    float e0 = __expf(p0*0.25f + bias0);
    float e1 = __expf(p1*0.25f + bias1);
    z0 += e0; z1 += e1;
    a0 += e0*b2f(vm[so+lane]);
    a1 += e1*b2f(vm[so+64+lane]);
  }
  float inv0 = 1.f/(z0 + 1e-9f);
  float inv1 = 1.f/(z1 + 1e-9f);
  agg[dq+lane]    = a0*inv0;
  agg[dq+64+lane] = a1*inv1;
}

// Fused meta-learner over [meta_out (Ma rows, f32) | mef (bf16)] — wide launch.
__global__ __launch_bounds__(128) void learner2(
    const float* __restrict__ Xa, const unsigned short* __restrict__ Xb, int Ma,
    const void* __restrict__ u, const void* __restrict__ W2,
    const void* __restrict__ W1,
    float* __restrict__ p2a, float* __restrict__ p1a,
    unsigned short* __restrict__ w2me, unsigned short* __restrict__ p1b,
    const float* __restrict__ base, const int* __restrict__ dflag)
{
  __shared__ float sX[128];
  __shared__ float st[16];
  __shared__ float sw[16];
  const bool wf32 = (*dflag) != 0;
  const int blk = blockIdx.x, t = threadIdx.x;
  const bool isB = (blk >= Ma);
  const int m = isB ? (blk - Ma) : blk;
  if (isB) sX[t] = b2f(Xb[(size_t)m*DD + t]);
  else     sX[t] = Xa[(size_t)m*DD + t];
  __syncthreads();
  int l = t>>3, j = t&7;
  float part = 0.f;
  for (int d=j*16; d<j*16+16; d++) part += sX[d]*gld(u, l*128+d, wf32);
  part += __shfl_xor(part,1,64); part += __shfl_xor(part,2,64); part += __shfl_xor(part,4,64);
  if (j==0) st[l] = part * 0.08838834764831845f;
  __syncthreads();
  float mx=-1e30f;
  for (int i=0;i<16;i++) mx = fmaxf(mx, st[i]);
  float ssum=0.f;
  for (int i=0;i<16;i++) ssum += __expf(st[i]-mx);
  float inv = 1.f/ssum;
  if (t<16) sw[t] = __expf(st[t]-mx)*inv;
  __syncthreads();
  float a=0.f;
  for (int i=0;i<16;i++) a += sw[i]*gld(W2, i*128+t, wf32);
  if (isB) w2me[(size_t)m*DD+t] = f2b(base[152+t] + a);
  else     p2a[(size_t)m*DD+t] = a;
  if (t<8){
    float bb=0.f;
    for (int i=0;i<16;i++) bb += sw[i]*gld(W1, i*8+t, wf32);
    if (isB) p1b[(size_t)m*HH+t] = f2b(bb);
    else     p1a[(size_t)m*HH+t] = bb;
  }
}

// ---------------- big-graph: fused scores+agg, fp8 kv, packed indices ----------
// ONE 16-lane group per dst node (4 concurrent nodes per wave — no cross-group
// reduce, 4 independent gather streams). agg written PRE-NORMALIZED
// (0.125 fp8 v-descale folded into 1/z; no z round-trip).
__global__ __launch_bounds__(256) void edge_fused(
    const int* __restrict__ rowptr, const int* __restrict__ epack,
    const int* __restrict__ mnid,
    const unsigned short* __restrict__ q, const unsigned char* __restrict__ kv8,
    const unsigned short* __restrict__ w2me, const unsigned short* __restrict__ p1me,
    const float* __restrict__ p1mn, const float* __restrict__ base,
    unsigned short* __restrict__ aggb, int N)
{
  int wv = blockIdx.x*4 + (threadIdx.x>>6);
  int lane = threadIdx.x & 63;
  int grp = lane >> 4, l16 = lane & 15;
  int d = wv*4 + grp;                 // each 16-lane group owns one dst node
  if (d >= N) return;
  int c8 = l16 * 8;
  int h = l16 >> 1;

  int i0 = rowptr[d], i1 = rowptr[d+1];
  float bias = base[16+h] + base[8+h] + p1mn[(size_t)mnid[d]*HH + h];
  size_t dq = (size_t)d*DD;
  float qv[8];
  {
    uint4 qraw = *(const uint4*)(q + dq + c8);
    const unsigned short* qh = (const unsigned short*)&qraw;
#pragma unroll
    for (int j=0;j<8;j++) qv[j] = b2f(qh[j])*0.03125f;  // 0.25 * 1/8 (k fp8 scale)
  }

  float zh = 0.f;
  float a[8];
#pragma unroll
  for (int j=0;j<8;j++) a[j] = 0.f;

  int i = i0;
  for (; i + 1 < i1; i += 2){
    unsigned int v0p = (unsigned int)epack[i];
    unsigned int v1p = (unsigned int)epack[i+1];
    int s0 = v0p & 0x1FFFF, me0 = v0p >> 17;
    int s1 = v1p & 0x1FFFF, me1 = v1p >> 17;
    size_t kvo0 = (size_t)s0*256, mo0 = (size_t)me0*DD;
    size_t kvo1 = (size_t)s1*256, mo1 = (size_t)me1*DD;
    uint2 kraw0 = *(const uint2*)(kv8 + kvo0 + c8);
    uint2 vraw0 = *(const uint2*)(kv8 + kvo0 + 128 + c8);
    uint4 wraw0 = *(const uint4*)(w2me + mo0 + c8);
    float pm0 = b2f(p1me[(size_t)me0*HH + h]);
    uint2 kraw1 = *(const uint2*)(kv8 + kvo1 + c8);
    uint2 vraw1 = *(const uint2*)(kv8 + kvo1 + 128 + c8);
    uint4 wraw1 = *(const uint4*)(w2me + mo1 + c8);
    float pm1 = b2f(p1me[(size_t)me1*HH + h]);
    float k0f[8], v0f[8], k1f[8], v1f[8];
    cvt4(kraw0.x, k0f); cvt4(kraw0.y, k0f+4);
    cvt4(vraw0.x, v0f); cvt4(vraw0.y, v0f+4);
    cvt4(kraw1.x, k1f); cvt4(kraw1.y, k1f+4);
    cvt4(vraw1.x, v1f); cvt4(vraw1.y, v1f+4);
    const unsigned short* wh0 = (const unsigned short*)&wraw0;
    const unsigned short* wh1 = (const unsigned short*)&wraw1;
    float pA = 0.f, pB = 0.f;
#pragma unroll
    for (int j=0;j<8;j++){
      pA += qv[j]*(k0f[j]*b2f(wh0[j]));
      pB += qv[j]*(k1f[j]*b2f(wh1[j]));
    }
    pA += __shfl_xor(pA, 1, 64);
    pB += __shfl_xor(pB, 1, 64);
    float ex0 = __expf(pA + bias + pm0);
    float ex1 = __expf(pB + bias + pm1);
    zh += ex0 + ex1;
#pragma unroll
    for (int j=0;j<8;j++) a[j] += ex0*v0f[j] + ex1*v1f[j];
  }
  if (i < i1){
    unsigned int vp = (unsigned int)epack[i];
    int s = vp & 0x1FFFF, me = vp >> 17;
    size_t kvo = (size_t)s*256, mo = (size_t)me*DD;
    uint2 kraw = *(const uint2*)(kv8 + kvo + c8);
    uint2 vraw = *(const uint2*)(kv8 + kvo + 128 + c8);
    uint4 wraw = *(const uint4*)(w2me + mo + c8);
    float pm = b2f(p1me[(size_t)me*HH + h]);
    float kf[8], vf[8];
    cvt4(kraw.x, kf); cvt4(kraw.y, kf+4);
    cvt4(vraw.x, vf); cvt4(vraw.y, vf+4);
    const unsigned short* wh = (const unsigned short*)&wraw;
    float p = 0.f;
#pragma unroll
    for (int j=0;j<8;j++) p += qv[j]*(kf[j]*b2f(wh[j]));
    p += __shfl_xor(p, 1, 64);
    float ex = __expf(p + bias + pm);
    zh += ex;
#pragma unroll
    for (int j=0;j<8;j++) a[j] += ex*vf[j];
  }

  // each lane owns its 8 channels; zh is per-head (same in both pair lanes)
  float inv = 0.125f / (zh + 1e-9f);   // fp8 v-descale folded into 1/z
  us8 o;
#pragma unroll
  for (int j=0;j<8;j++) o.s[j] = f2b(a[j]*inv);
  *(us8*)(aggb + dq + c8) = o;
}

// One 16-lane group per target; vectorized feat row read + shuffle reduce.
__global__ __launch_bounds__(256) void readout(
    const int* __restrict__ tgt, const int* __restrict__ mnid,
    const unsigned short* __restrict__ featb, const float* __restrict__ p1mn,
    const float* __restrict__ base, float* __restrict__ acc,
    void* __restrict__ out, int last, float invNB, int BT,
    const int* __restrict__ dflag)
{
  int t = blockIdx.x*256 + threadIdx.x;
  int ti = t >> 4, l16 = t & 15;
  if (ti >= BT) return;
  int idx = tgt[ti]; int mn = mnid[idx];
  int h = l16 >> 1;
  float tw = base[h] + p1mn[(size_t)mn*HH + h];
  uint4 raw = *(const uint4*)(featb + (size_t)idx*DD + l16*8);
  const unsigned short* hw = (const unsigned short*)&raw;
  float s = 0.f;
#pragma unroll
  for (int j=0;j<8;j++) s += b2f(hw[j]);
  float part = tw * s;
  part += __shfl_xor(part, 1, 64);
  part += __shfl_xor(part, 2, 64);
  part += __shfl_xor(part, 4, 64);
  part += __shfl_xor(part, 8, 64);
  if (l16 == 0){
    if (!last) acc[ti] = part;
    else {
      float r = (acc[ti] + part) * invNB;
      if ((*dflag) != 0) ((float*)out)[ti] = r;
      else ((__hip_bfloat16*)out)[ti] = __float2bfloat16(r);
    }
  }
}

extern "C" void kernel_launch(void* const* d_in, const int* in_sizes, int n_in,
                              void* d_out, int out_size, void* d_ws, size_t ws_size,
                              hipStream_t stream) {
  const void* emb   = d_in[0];
  const void* u     = d_in[1];
  const void* W2lat = d_in[2];
  const void* W1lat = d_in[3];
  WPtrs wptrs;
  for (int i=0;i<8;i++) wptrs.p[i] = d_in[4+i];
  const int* node_vals      = (const int*)d_in[12];
  const int* meta_node_vals = (const int*)d_in[13];
  const int* src            = (const int*)d_in[14];
  const int* dst            = (const int*)d_in[15];
  const int* meta_src       = (const int*)d_in[16];
  const int* meta_dst       = (const int*)d_in[17];
  const int* meta_node_id   = (const int*)d_in[18];
  const int* meta_edge_id   = (const int*)d_in[19];
  const int* target_idx     = (const int*)d_in[20];
  const int* static_vals    = (const int*)d_in[21];
  const int* static_src     = (const int*)d_in[22];
  const int* static_dst     = (const int*)d_in[23];

  const int N  = in_sizes[12];
  const int MN = in_sizes[13];
  const int E  = in_sizes[14];
  const int ME = in_sizes[16];
  const int BT = in_sizes[20];
  const int NSRC = in_sizes[22];
  const int NB = in_sizes[8] / (DD*DD);

  float* ws = (float*)d_ws;
  size_t off = 0;
  // keep every allocation 16B-aligned (global_load_lds sources need it)
  auto allocf = [&](size_t n){ float* p = ws + off; off += (n + 3) & ~(size_t)3; return p; };
  auto allocb = [&](size_t n){ unsigned short* p = (unsigned short*)(ws + off); off += (((n+1)/2) + 3) & ~(size_t)3; return p; };
  auto alloci = [&](size_t n){ int* p = (int*)(ws + off); off += (n + 3) & ~(size_t)3; return p; };
  int*            dflag = (int*)ws; off += 4;
  unsigned short* feat  = allocb((size_t)N*DD);
  unsigned short* q     = allocb((size_t)N*DD);
  unsigned char*  kv8   = (unsigned char*)allocf((size_t)N*64);  // N x 256B fp8 rows
  unsigned short* aggb  = allocb((size_t)N*DD);
  float*          meta_feat= allocf((size_t)MN*DD);
  float*          agg_m = allocf((size_t)MN*DD);
  unsigned short* q_m   = allocb((size_t)MN*DD);
  unsigned short* kf_m  = allocb((size_t)MN*DD);
  unsigned short* v_m   = allocb((size_t)MN*DD);
  float*          meta_out = allocf((size_t)MN*DD);
  unsigned short* mef   = allocb((size_t)ME*DD);
  float*          p2mn  = allocf((size_t)MN*DD);
  float*          p1mn  = allocf((size_t)MN*HH);
  unsigned short* w2me  = allocb((size_t)ME*DD);
  unsigned short* p1me  = allocb((size_t)ME*HH);
  float*          base  = allocf(280);
  float*          acc   = allocf((size_t)BT);
  unsigned short* wstage= allocb((size_t)8*NB*DD*DD);
  int*            rowptr= alloci((size_t)N+1);
  int*            cursor= alloci((size_t)N);
  int*            epack = alloci((size_t)E);
  int*            rowptr_m= alloci((size_t)MN+1);
  int*            cursor_m= alloci((size_t)MN);
  int*            esrc_m  = alloci((size_t)ME);
  int*            eorig_m = alloci((size_t)ME);
  int*            degAll  = alloci((size_t)(N+MN));
  int*            deg     = degAll;
  int*            deg_m   = degAll + N;
  const int nb_scan   = (N + 1023)/1024;
  const int nb_scan_m = (MN + 1023)/1024;
  int*            bsum   = alloci((size_t)nb_scan);
  int*            bsum_m = alloci((size_t)nb_scan_m);
  (void)ws_size; (void)n_in; (void)out_size;

  const float* base_n2 = base + 24;

  k_static<<<1,256,0,stream>>>(emb, static_vals, static_src, static_dst,
                               u, W2lat, W1lat, base, NSRC, dflag);
  gather_rows2<<<((N+MN)*16+255)/256,256,0,stream>>>(emb, node_vals, feat, N,
      meta_node_vals, meta_feat, MN, dflag);

  const int nbE  = (E+255)/256, nbME = (ME+255)/256;
  const int nb3B = (N+255)/256, nb3M = (MN+255)/256;
  zeroi<<<(N+MN+255)/256,256,0,stream>>>(degAll, N+MN);
  k_hist2<<<nbE+nbME,256,0,stream>>>(dst, meta_dst, deg, deg_m, E, ME, nbE);
  k_scan1b<<<nb_scan+nb_scan_m,256,0,stream>>>(deg, rowptr, bsum, N, nb_scan,
      deg_m, rowptr_m, bsum_m, MN);
  k_scan3b<<<nb3B+nb3M,256,0,stream>>>(rowptr, bsum, cursor, N, nb3B, nb_scan,
      rowptr_m, bsum_m, cursor_m, MN, nb_scan_m);
  k_scatter2<<<nbE+nbME,256,0,stream>>>(dst, src, meta_edge_id, cursor,
      epack, E, nbE, meta_dst, meta_src, cursor_m, esrc_m, eorig_m, ME);

  w_repack16<<<8*NB*64,256,0,stream>>>(wptrs, wstage, NB, dflag);

  const int gm = (MN+63)/64;
  const int gN = (N+63)/64;
  const float invNB = 1.0f/(float)NB;

  for (int b=0;b<NB;b++){
    const unsigned short* wq_m = wstage + (size_t)(0*NB+b)*DD*DD;
    const unsigned short* wk_m = wstage + (size_t)(1*NB+b)*DD*DD;
    const unsigned short* wv_m = wstage + (size_t)(2*NB+b)*DD*DD;
    const unsigned short* wo_m = wstage + (size_t)(3*NB+b)*DD*DD;
    const unsigned short* wqb  = wstage + (size_t)(4*NB+b)*DD*DD;
    const unsigned short* wkb  = wstage + (size_t)(5*NB+b)*DD*DD;
    const unsigned short* wvb  = wstage + (size_t)(6*NB+b)*DD*DD;
    const unsigned short* wob  = wstage + (size_t)(7*NB+b)*DD*DD;

    // ---- meta conv (CSR, atomic-free) ----
    gemm_qkv<EPI_SCALE_CONST,false,false><<<gm,256,0,stream>>>(meta_feat,
        wq_m, wk_m, wv_m, q_m, kf_m, DD, v_m, DD, MN, base_n2, nullptr, nullptr);
    edge_meta_csr<<<(MN+3)/4,256,0,stream>>>(rowptr_m, esrc_m, eorig_m,
        q_m, kf_m, v_m, base, mef, agg_m, MN);
    // meta Wo: meta_out = relu(agg_m@Wo) (f32, agg pre-normalized); meta_feat += relu
    gemm128m<EPI_RELU_RES2,false,false><<<gm,256,0,stream>>>(agg_m, wo_m,
        meta_out, MN, nullptr, meta_feat, meta_feat);
    // wide fused learners: MN rows (f32 meta_out) + ME rows (bf16 mef)
    learner2<<<MN+ME,128,0,stream>>>(meta_out, mef, MN, u, W2lat, W1lat,
        p2mn, p1mn, w2me, p1me, base, dflag);

    // ---- big conv (fp8 kv) ----
    gemm_qkv<EPI_SCALE_GATHER,true,true><<<gN,256,0,stream>>>(feat, wqb, wkb, wvb,
        q, kv8, 0, kv8 + 128, 0, N, base_n2, p2mn, meta_node_id);
    edge_fused<<<(N+15)/16,256,0,stream>>>(rowptr, epack,
        meta_node_id, q, kv8, w2me, p1me, p1mn, base, aggb, N);
    gemm128m<EPI_RELU_RES,true,true><<<gN,256,0,stream>>>(aggb, wob, feat, N,
        feat, nullptr, nullptr);

    // ---- readout ----
    readout<<<(BT*16+255)/256,256,0,stream>>>(target_idx, meta_node_id, feat, p1mn,
        base, acc, d_out, (b==NB-1) ? 1 : 0, invNB, BT, dflag);
  }
}

// Round 3
// 573.863 us; speedup vs baseline: 1.2145x; 1.1291x over previous
//
#include <hip/hip_runtime.h>
#include <hip/hip_bf16.h>
#include <hip/hip_fp8.h>

#define DD   128
#define HH   8

typedef short bf16x8 __attribute__((ext_vector_type(8)));
typedef float f32x4  __attribute__((ext_vector_type(4)));
typedef float f32x2  __attribute__((ext_vector_type(2)));

__device__ __forceinline__ float b2f(unsigned short v){
  union { unsigned int u; float f; } x; x.u = ((unsigned int)v) << 16; return x.f;
}
__device__ __forceinline__ unsigned short f2b(float f){
  __hip_bfloat16 h = __float2bfloat16(f);
  return *(unsigned short*)&h;
}
__device__ __forceinline__ unsigned char f2f8(float x){
  __hip_fp8_e4m3 h(x);
  return h.__x;
}
__device__ __forceinline__ float f82f(unsigned char b){
  __hip_fp8_e4m3 h; h.__x = b;
  return (float)h;
}
// 4 fp8 bytes (one u32) -> 4 floats; HW packed cvt when available.
__device__ __forceinline__ void cvt4(unsigned int w, float* o){
#if defined(__has_builtin)
# if __has_builtin(__builtin_amdgcn_cvt_pk_f32_fp8)
  f32x2 lo = __builtin_amdgcn_cvt_pk_f32_fp8((int)w, false);
  f32x2 hi = __builtin_amdgcn_cvt_pk_f32_fp8((int)w, true);
  o[0]=lo[0]; o[1]=lo[1]; o[2]=hi[0]; o[3]=hi[1];
  return;
# endif
#endif
  o[0]=f82f(w&0xff); o[1]=f82f((w>>8)&0xff);
  o[2]=f82f((w>>16)&0xff); o[3]=f82f((w>>24)&0xff);
}
struct __align__(8) us4 { unsigned short x,y,z,w; };
struct __align__(16) us8 { unsigned short s[8]; };

__device__ __forceinline__ float gld(const void* p, size_t i, bool f32){
  if (f32) return ((const float*)p)[i];
  return b2f(((const unsigned short*)p)[i]);
}

// async global->LDS, 16B per lane (wave-uniform LDS base + lane*16)
__device__ __forceinline__ void gll16(const void* g, void* l){
  __builtin_amdgcn_global_load_lds(
      (const __attribute__((address_space(1))) unsigned int*)g,
      (__attribute__((address_space(3))) unsigned int*)l, 16, 0, 0);
}

// ALL weight blocks (8 tensors x NB matrices) -> bf16 TRANSPOSED staging, one launch.
struct WPtrs { const void* p[8]; };
__global__ __launch_bounds__(256) void w_repack16(
    WPtrs W, unsigned short* __restrict__ stage, int NBt,
    const int* __restrict__ dflag)
{
  const bool wf32 = (*dflag) != 0;
  int idx = blockIdx.x >> 6;
  int ti = idx / NBt, bi = idx - ti*NBt;
  size_t bo = (size_t)bi*DD*DD;
  int i = (blockIdx.x & 63)*256 + threadIdx.x;
  int k = i >> 7, n = i & 127;
  float x;
  if (wf32) x = ((const float*)W.p[ti])[bo + i];
  else      x = b2f(((const unsigned short*)W.p[ti])[bo + i]);
  stage[(size_t)idx*DD*DD + n*DD + k] = f2b(x);
}

enum { EPI_STORE=0, EPI_SCALE_CONST=1, EPI_RELU=3,
       EPI_RELU_RES=4, EPI_RELU_RES2=5 };

#define CPAD 132

// ===== shared GEMM building blocks: linear LDS + XOR chunk swizzle =====
// LDS layout: row r (128 bf16 = 256B = 16 chunks of 16B); logical chunk c is
// stored at chunk c ^ (r&7).  Written either by global_load_lds with the
// inverse-swizzled per-lane GLOBAL address (linear LDS dest), or by ds_write
// at the swizzled offset.  Fragment reads use offset  kk ^ ((am&7)<<3).

// C[M,128] = epi( A[M,128] @ B[128,128] ), B bf16 TRANSPOSED ([n][k]).
// EPI_RELU_RES : C = relu(x) + Rb(bf16)                  [big Wo, OUTB=1]
// EPI_RELU_RES2: Cv = relu(x) f32; C2 = relu(x)+Rf (f32) [meta Wo, OUTB=0]
template<int EPI, bool INB, bool OUTB>
__global__ __launch_bounds__(256) void gemm128m(
    const void* __restrict__ Av, const unsigned short* __restrict__ Bt,
    void* __restrict__ Cv, int M,
    const unsigned short* __restrict__ Rb,
    const float* __restrict__ Rf, float* __restrict__ C2)
{
  __shared__ __align__(16) unsigned short Asb[64*128];
  __shared__ __align__(16) unsigned short Btb[16896];  // B: 32KB / C: 64x132 f32
  const int tid = threadIdx.x;
  const int wave = tid >> 6, lane = tid & 63;
  const int row0 = blockIdx.x * 64;

  if (INB){
    const char* Ab = (const char*)Av;
    int n4 = lane >> 4, c = lane & 15;
#pragma unroll
    for (int op=0; op<4; op++){
      int rA = wave*16 + op*4;
      int n = rA + n4;
      int gr = row0 + n; if (gr >= M) gr = M - 1;
      gll16(Ab + (size_t)gr*256 + ((size_t)((c ^ (n & 7)) << 4)), &Asb[rA*128]);
    }
  } else {
    const float* Af = (const float*)Av;
    int r = tid >> 2, cb = (tid & 3) * 32, rx = (r & 7) << 3;
    int gr = row0 + r;
#pragma unroll
    for (int j=0;j<8;j++){
      int cc = cb + j*4;
      float4 val = make_float4(0.f,0.f,0.f,0.f);
      if (gr < M) val = *(const float4*)(Af + (size_t)gr*DD + cc);
      us4 o; o.x=f2b(val.x); o.y=f2b(val.y); o.z=f2b(val.z); o.w=f2b(val.w);
      *(us4*)&Asb[r*128 + (cc ^ rx)] = o;
    }
  }
  {
    int n4 = lane >> 4, c = lane & 15;
#pragma unroll
    for (int op=0; op<8; op++){
      int rB = wave*32 + op*4;
      int n = rB + n4;
      gll16((const char*)Bt + (size_t)n*256 + ((size_t)((c ^ (n & 7)) << 4)),
            &Btb[rB*128]);
    }
  }
  __syncthreads();

  f32x4 acc[8];
#pragma unroll
  for (int t=0;t<8;t++) acc[t] = (f32x4){0.f,0.f,0.f,0.f};
  const int am = (lane & 15), kq = (lane >> 4) * 8, axr = (am & 7) << 3;
#pragma unroll
  for (int k0=0;k0<128;k0+=32){
    int xo = (k0 + kq) ^ axr;
    bf16x8 a = *(bf16x8*)&Asb[(wave*16 + am)*128 + xo];
#pragma unroll
    for (int t=0;t<8;t++){
      bf16x8 b = *(bf16x8*)&Btb[(t*16 + am)*128 + xo];
      acc[t] = __builtin_amdgcn_mfma_f32_16x16x32_bf16(a, b, acc[t], 0,0,0);
    }
  }
  __syncthreads();
  float* Cls = (float*)Btb;
  {
    int rr = wave*16 + (lane>>4)*4;
    int cc = lane & 15;
#pragma unroll
    for (int t=0;t<8;t++)
#pragma unroll
      for (int r=0;r<4;r++)
        Cls[(rr + r)*CPAD + t*16 + cc] = acc[t][r];
  }
  __syncthreads();

  {
    int r = tid >> 2, cb = (tid & 3) * 32;
    int gr = row0 + r;
    if (gr < M){
#pragma unroll
      for (int j=0;j<8;j++){
        int c = cb + j*4;
        float4 o = *(float4*)&Cls[r*CPAD + c];
        if (EPI == EPI_RELU_RES){
          us4 rb = *(const us4*)(Rb + (size_t)gr*DD + c);
          o.x=fmaxf(o.x,0.f)+b2f(rb.x); o.y=fmaxf(o.y,0.f)+b2f(rb.y);
          o.z=fmaxf(o.z,0.f)+b2f(rb.z); o.w=fmaxf(o.w,0.f)+b2f(rb.w);
        } else if (EPI == EPI_RELU_RES2){
          o.x=fmaxf(o.x,0.f); o.y=fmaxf(o.y,0.f); o.z=fmaxf(o.z,0.f); o.w=fmaxf(o.w,0.f);
          float4 rf = *(const float4*)(Rf + (size_t)gr*DD + c);
          *(float4*)(C2 + (size_t)gr*DD + c) =
              make_float4(o.x+rf.x, o.y+rf.y, o.z+rf.z, o.w+rf.w);
        }
        if (OUTB){
          us4 ob; ob.x=f2b(o.x); ob.y=f2b(o.y); ob.z=f2b(o.z); ob.w=f2b(o.w);
          *(us4*)((unsigned short*)Cv + (size_t)gr*DD + c) = ob;
        } else {
          *(float4*)((float*)Cv + (size_t)gr*DD + c) = o;
        }
      }
    }
  }
}

// Fused Q/K/V gemm body. FP8KV: phases 1/2 write fp8 (x8 scale), 256B/row.
// EPIQ==EPI_SCALE_CONST: phase-0 scaled by svec. EPI_STORE: plain store.
template<int EPIQ, bool INB, bool FP8KV>
__device__ __forceinline__ void qkv_body(
    unsigned short* Asb, unsigned short* Btb, int blk,
    const void* __restrict__ Av,
    const unsigned short* __restrict__ Btq, const unsigned short* __restrict__ Btk,
    const unsigned short* __restrict__ Btv,
    void* __restrict__ Cq, void* __restrict__ Ck, int stK,
    void* __restrict__ Cvo, int stV, int M,
    const float* __restrict__ svec)
{
  const int tid = threadIdx.x;
  const int wave = tid >> 6, lane = tid & 63;
  const int row0 = blk * 64;

  if (INB){
    const char* Ab = (const char*)Av;
    int n4 = lane >> 4, c = lane & 15;
#pragma unroll
    for (int op=0; op<4; op++){
      int rA = wave*16 + op*4;
      int n = rA + n4;
      int gr = row0 + n; if (gr >= M) gr = M - 1;
      gll16(Ab + (size_t)gr*256 + ((size_t)((c ^ (n & 7)) << 4)), &Asb[rA*128]);
    }
  } else {
    const float* Af = (const float*)Av;
    int r = tid >> 2, cb = (tid & 3) * 32, rx = (r & 7) << 3;
    int gr = row0 + r;
#pragma unroll
    for (int j=0;j<8;j++){
      int cc = cb + j*4;
      float4 val = make_float4(0.f,0.f,0.f,0.f);
      if (gr < M) val = *(const float4*)(Af + (size_t)gr*DD + cc);
      us4 o; o.x=f2b(val.x); o.y=f2b(val.y); o.z=f2b(val.z); o.w=f2b(val.w);
      *(us4*)&Asb[r*128 + (cc ^ rx)] = o;
    }
  }

  const unsigned short* Bts[3] = {Btq, Btk, Btv};
  void* Cs[3] = {Cq, Ck, Cvo};
  const int sts[3] = {DD, stK, stV};
  const int am = (lane & 15), kq = (lane >> 4) * 8, axr = (am & 7) << 3;

  for (int ph=0; ph<3; ph++){
    {
      const unsigned short* Bt = Bts[ph];
      int n4 = lane >> 4, c = lane & 15;
#pragma unroll
      for (int op=0; op<8; op++){
        int rB = wave*32 + op*4;
        int n = rB + n4;
        gll16((const char*)Bt + (size_t)n*256 + ((size_t)((c ^ (n & 7)) << 4)),
              &Btb[rB*128]);
      }
    }
    __syncthreads();
    f32x4 acc[8];
#pragma unroll
    for (int t=0;t<8;t++) acc[t] = (f32x4){0.f,0.f,0.f,0.f};
#pragma unroll
    for (int k0=0;k0<128;k0+=32){
      int xo = (k0 + kq) ^ axr;
      bf16x8 a = *(bf16x8*)&Asb[(wave*16 + am)*128 + xo];
#pragma unroll
      for (int t=0;t<8;t++){
        bf16x8 b = *(bf16x8*)&Btb[(t*16 + am)*128 + xo];
        acc[t] = __builtin_amdgcn_mfma_f32_16x16x32_bf16(a, b, acc[t], 0,0,0);
      }
    }
    __syncthreads();
    float* Cls = (float*)Btb;
    {
      int rr = wave*16 + (lane>>4)*4;
      int cc = lane & 15;
#pragma unroll
      for (int t=0;t<8;t++)
#pragma unroll
        for (int r=0;r<4;r++)
          Cls[(rr + r)*CPAD + t*16 + cc] = acc[t][r];
    }
    __syncthreads();
    {
      int r = tid >> 2, cb = (tid & 3) * 32;
      int gr = row0 + r;
      if (gr < M){
#pragma unroll
        for (int j=0;j<8;j++){
          int c = cb + j*4;
          float4 o = *(float4*)&Cls[r*CPAD + c];
          if (ph == 0 && EPIQ == EPI_SCALE_CONST){
            o.x*=svec[c+0]; o.y*=svec[c+1]; o.z*=svec[c+2]; o.w*=svec[c+3];
          }
          if (FP8KV && ph > 0){
            unsigned char* Cb = (unsigned char*)Cs[ph];
            uchar4 ob;
            ob.x=f2f8(o.x*8.f); ob.y=f2f8(o.y*8.f);
            ob.z=f2f8(o.z*8.f); ob.w=f2f8(o.w*8.f);
            *(uchar4*)(Cb + (size_t)gr*256 + c) = ob;
          } else {
            us4 ob; ob.x=f2b(o.x); ob.y=f2b(o.y); ob.z=f2b(o.z); ob.w=f2b(o.w);
            *(us4*)((unsigned short*)Cs[ph] + (size_t)gr*sts[ph] + c) = ob;
          }
        }
      }
    }
    __syncthreads();
  }
}

// Merged big+meta QKV in one dispatch: blocks [0,gN) big graph (bf16 in,
// fp8 kv out, plain q store — head scale deferred to edge_fused);
// blocks [gN, gN+gm) meta graph (f32 in, const-scaled q, bf16 out).
__global__ __launch_bounds__(256) void gemm_qkv2(
    const unsigned short* __restrict__ featB, const float* __restrict__ featM,
    const unsigned short* __restrict__ wqb, const unsigned short* __restrict__ wkb,
    const unsigned short* __restrict__ wvb,
    const unsigned short* __restrict__ wqm, const unsigned short* __restrict__ wkm,
    const unsigned short* __restrict__ wvm,
    unsigned short* __restrict__ qB, unsigned char* __restrict__ kv8,
    unsigned short* __restrict__ qM, unsigned short* __restrict__ kfM,
    unsigned short* __restrict__ vM,
    int Nbig, int Nmeta, int gN, const float* __restrict__ svec)
{
  __shared__ __align__(16) unsigned short Asb[64*128];
  __shared__ __align__(16) unsigned short Btb[16896];
  if (blockIdx.x < gN){
    qkv_body<EPI_STORE,true,true>(Asb, Btb, blockIdx.x, featB,
        wqb, wkb, wvb, qB, kv8, 0, kv8 + 128, 0, Nbig, svec);
  } else {
    qkv_body<EPI_SCALE_CONST,false,false>(Asb, Btb, blockIdx.x - gN, featM,
        wqm, wkm, wvm, qM, kfM, DD, vM, DD, Nmeta, svec);
  }
}

// Static param-name graph -> base params.  (k_detect fused in.)
__global__ __launch_bounds__(256) void k_static(
    const void* __restrict__ emb, const int* __restrict__ svals,
    const int* __restrict__ ssrc, const int* __restrict__ sdst,
    const void* __restrict__ u, const void* __restrict__ W2,
    const void* __restrict__ W1, float* __restrict__ base, int nsrc,
    int* __restrict__ dflag)
{
  __shared__ float sagg[15][128];
  __shared__ float ssc[15][16];
  __shared__ float sww[15][16];
  __shared__ int swf;
  const int t = threadIdx.x;
  if (t < 64){
    float m = 0.f;
    for (int i=t; i<128; i+=64){
      float x = fabsf(b2f(((const unsigned short*)emb)[i]));
      if (x < 1e30f) m = fmaxf(m, x);
    }
#pragma unroll
    for (int s=1;s<64;s<<=1) m = fmaxf(m, __shfl_xor(m, s, 64));
    if (t==0){ int f = (m > 1e4f) ? 1 : 0; *dflag = f; swf = f; }
  }
  for (int i=t;i<15*128;i+=256) ((float*)sagg)[i]=0.f;
  __syncthreads();
  const bool wf32 = (swf != 0);
  if (t < 128){
    for (int i=0;i<nsrc;i++){
      int row = sdst[i]; int vr = svals[ssrc[i]];
      sagg[row][t] += gld(emb, (size_t)vr*DD + t, wf32);
    }
  }
  __syncthreads();
  if (t < 240){
    int n = t>>4, l = t&15;
    float a=0.f;
    for (int d=0;d<128;d++) a += sagg[n][d]*gld(u, l*128+d, wf32);
    ssc[n][l] = a * 0.08838834764831845f;
  }
  __syncthreads();
  if (t < 15){
    float mx=-1e30f;
    for (int l=0;l<16;l++) mx = fmaxf(mx, ssc[t][l]);
    float s=0.f;
    for (int l=0;l<16;l++){ float e=__expf(ssc[t][l]-mx); sww[t][l]=e; s+=e; }
    float inv = 1.f/s;
    for (int l=0;l<16;l++) sww[t][l]*=inv;
  }
  __syncthreads();
  if (t < 8){
    float a=0.f,b=0.f,c=0.f;
    for (int l=0;l<16;l++){
      float wv = gld(W1, l*8+t, wf32);
      a += sww[0][l]*wv; b += sww[3][l]*wv; c += sww[9][l]*wv;
    }
    base[t]=a; base[8+t]=b; base[16+t]=c;
  }
  if (t < 128){
    float a=0.f,b=0.f;
    for (int l=0;l<16;l++){
      float wv = gld(W2, l*128+t, wf32);
      a += sww[6][l]*wv; b += sww[12][l]*wv;
    }
    base[24+t]=a; base[152+t]=b;
  }
}

// Merged gather: big graph rows -> bf16 feat; meta rows -> f32 meta_feat.
__global__ __launch_bounds__(256) void gather_rows2(
    const void* __restrict__ emb,
    const int* __restrict__ valsB, unsigned short* __restrict__ featB, int nB,
    const int* __restrict__ valsM, float* __restrict__ featM, int nM,
    const int* __restrict__ dflag)
{
  const bool wf32 = (*dflag) != 0;
  int i = blockIdx.x*256 + threadIdx.x;
  bool big = (i < nB*16);
  int i2 = big ? i : (i - nB*16);
  if (!big && i2 >= nM*16) return;
  int r = i2>>4, c = (i2&15)*8;
  int vr = big ? valsB[r] : valsM[r];
  float vb[8];
  if (wf32){
    float4 f0 = *(const float4*)((const float*)emb + (size_t)vr*DD + c);
    float4 f1 = *(const float4*)((const float*)emb + (size_t)vr*DD + c + 4);
    vb[0]=f0.x; vb[1]=f0.y; vb[2]=f0.z; vb[3]=f0.w;
    vb[4]=f1.x; vb[5]=f1.y; vb[6]=f1.z; vb[7]=f1.w;
  } else {
    uint4 raw = *(const uint4*)((const unsigned short*)emb + (size_t)vr*DD + c);
    const unsigned short* hw = (const unsigned short*)&raw;
#pragma unroll
    for (int j=0;j<8;j++) vb[j] = b2f(hw[j]);
  }
  if (big){
    unsigned short* d = featB + (size_t)r*DD + c;
    us4 o0, o1;
    o0.x=f2b(vb[0]); o0.y=f2b(vb[1]); o0.z=f2b(vb[2]); o0.w=f2b(vb[3]);
    o1.x=f2b(vb[4]); o1.y=f2b(vb[5]); o1.z=f2b(vb[6]); o1.w=f2b(vb[7]);
    *(us4*)d = o0; *(us4*)(d+4) = o1;
  } else {
    float* d = featM + (size_t)r*DD + c;
    *(float4*)d     = make_float4(vb[0],vb[1],vb[2],vb[3]);
    *(float4*)(d+4) = make_float4(vb[4],vb[5],vb[6],vb[7]);
  }
}

__global__ __launch_bounds__(256) void zeroi(int* __restrict__ p, int n){
  int i = blockIdx.x*256 + threadIdx.x;
  if (i < n) p[i] = 0;
}

// ---------------- merged CSR build (big + meta graphs) ----------------
__global__ __launch_bounds__(256) void k_hist2(
    const int* __restrict__ dstB, const int* __restrict__ dstM,
    int* __restrict__ degB, int* __restrict__ degM, int E, int ME, int nbE){
  int b = blockIdx.x, t = threadIdx.x;
  if (b < nbE){ int i = b*256+t; if (i < E) atomicAdd(&degB[dstB[i]], 1); }
  else { int i = (b-nbE)*256+t; if (i < ME) atomicAdd(&degM[dstM[i]], 1); }
}

__global__ __launch_bounds__(256) void k_scan1b(
    const int* __restrict__ degB, int* __restrict__ rpB, int* __restrict__ bsB,
    int nB, int nbB,
    const int* __restrict__ degM, int* __restrict__ rpM, int* __restrict__ bsM,
    int nM){
  __shared__ int ls[256];
  int blk = blockIdx.x, t = threadIdx.x;
  const int* deg; int* rowptr; int* bsum; int n; int b;
  if (blk < nbB){ deg=degB; rowptr=rpB; bsum=bsB; n=nB; b=blk; }
  else          { deg=degM; rowptr=rpM; bsum=bsM; n=nM; b=blk-nbB; }
  int base = b*1024 + t*4;
  int v0 = (base+0<n)?deg[base+0]:0;
  int v1 = (base+1<n)?deg[base+1]:0;
  int v2 = (base+2<n)?deg[base+2]:0;
  int v3 = (base+3<n)?deg[base+3]:0;
  int tsum = v0+v1+v2+v3;
  ls[t] = tsum; __syncthreads();
  for (int o=1;o<256;o<<=1){
    int x = (t>=o) ? ls[t-o] : 0;
    __syncthreads();
    ls[t] += x;
    __syncthreads();
  }
  int excl = ls[t]-tsum;
  if (t==255) bsum[b] = ls[255];
  if (base+0<n) rowptr[base+0]=excl;
  if (base+1<n) rowptr[base+1]=excl+v0;
  if (base+2<n) rowptr[base+2]=excl+v0+v1;
  if (base+3<n) rowptr[base+3]=excl+v0+v1+v2;
}

// scan3 with in-block prefix of block sums (scan2 merged in).
__global__ __launch_bounds__(256) void k_scan3b(
    int* __restrict__ rpB, const int* __restrict__ bsB, int* __restrict__ curB,
    int nB, int nb3B, int nbsB,
    int* __restrict__ rpM, const int* __restrict__ bsM, int* __restrict__ curM,
    int nM, int nbsM){
  __shared__ int spre;
  int blk = blockIdx.x, t = threadIdx.x;
  if (blk < nb3B){
    if (t == 0){
      int chunk = blk >> 2;
      int pre = 0;
      for (int j=0;j<chunk;j++) pre += bsB[j];
      spre = pre;
      if (blk == 0){
        int tot = 0;
        for (int j=0;j<nbsB;j++) tot += bsB[j];
        rpB[nB] = tot;
      }
    }
    __syncthreads();
    int i = blk*256 + t;
    if (i < nB){ int r = rpB[i] + spre; rpB[i] = r; curB[i] = r; }
  } else {
    int b2 = blk - nb3B;
    if (t == 0){
      int chunk = b2 >> 2;
      int pre = 0;
      for (int j=0;j<chunk;j++) pre += bsM[j];
      spre = pre;
      if (b2 == 0){
        int tot = 0;
        for (int j=0;j<nbsM;j++) tot += bsM[j];
        rpM[nM] = tot;
      }
    }
    __syncthreads();
    int i = b2*256 + t;
    if (i < nM){ int r = rpM[i] + spre; rpM[i] = r; curM[i] = r; }
  }
}

// scatter. Big graph: pack (src | meid<<17) into one int.
__global__ __launch_bounds__(256) void k_scatter2(
    const int* __restrict__ dstB, const int* __restrict__ srcB,
    const int* __restrict__ auxB, int* __restrict__ curB,
    int* __restrict__ epackB, int E, int nbE,
    const int* __restrict__ dstM, const int* __restrict__ srcM,
    int* __restrict__ curM, int* __restrict__ esrcM, int* __restrict__ eauxM,
    int ME){
  int blk = blockIdx.x, t = threadIdx.x;
  if (blk < nbE){
    int e = blk*256 + t;
    if (e < E){
      int p = atomicAdd(&curB[dstB[e]], 1);
      epackB[p] = srcB[e] | (auxB[e] << 17);
    }
  } else {
    int e = (blk-nbE)*256 + t;
    if (e < ME){
      int p = atomicAdd(&curM[dstM[e]], 1);
      esrcM[p] = srcM[e];
      eauxM[p] = e;
    }
  }
}

// ---------------- meta-graph edges: CSR, atomic-free, writes mef ----------------
// agg written PRE-NORMALIZED (softmax denominator folded in here).
__global__ __launch_bounds__(256) void edge_meta_csr(
    const int* __restrict__ rowptr, const int* __restrict__ esrc,
    const int* __restrict__ eorig,
    const unsigned short* __restrict__ qm, const unsigned short* __restrict__ kfm,
    const unsigned short* __restrict__ vm,
    const float* __restrict__ base, unsigned short* __restrict__ mef,
    float* __restrict__ agg, int NM)
{
  int d = blockIdx.x*4 + (threadIdx.x>>6);
  if (d >= NM) return;
  int lane = threadIdx.x & 63;
  const float* be2 = base+152; const float* be1 = base+16; const float* bn1 = base+8;
  size_t dq = (size_t)d*DD;
  float q0 = b2f(qm[dq+lane]), q1 = b2f(qm[dq+64+lane]);
  float w0 = be2[lane], w1 = be2[64+lane];
  int h0 = lane>>4, h1 = h0+4;
  float bias0 = be1[h0] + bn1[h0];
  float bias1 = be1[h1] + bn1[h1];
  float z0=0.f, z1=0.f, a0=0.f, a1=0.f;
  int i0 = rowptr[d], i1 = rowptr[d+1];
  for (int i=i0; i<i1; i++){
    int s = esrc[i], e = eorig[i];
    size_t so=(size_t)s*DD, eo=(size_t)e*DD;
    float ke0 = b2f(kfm[so+lane])    * w0;
    float ke1 = b2f(kfm[so+64+lane]) * w1;
    mef[eo+lane]=f2b(ke0); mef[eo+64+lane]=f2b(ke1);
    float p0 = q0*ke0, p1 = q1*ke1;
#pragma unroll
    for (int m=1;m<16;m<<=1){ p0 += __shfl_xor(p0,m,64); p1 += __shfl_xor(p1,m,64); }
    float e0 = __expf(p0*0.25f + bias0);
    float e1 = __expf(p1*0.25f + bias1);
    z0 += e0; z1 += e1;
    a0 += e0*b2f(vm[so+lane]);
    a1 += e1*b2f(vm[so+64+lane]);
  }
  float inv0 = 1.f/(z0 + 1e-9f);
  float inv1 = 1.f/(z1 + 1e-9f);
  agg[dq+lane]    = a0*inv0;
  agg[dq+64+lane] = a1*inv1;
}

// Fused meta-learner over [meta_out (Ma rows, f32) | mef (bf16)].
// 4 rows per block; u/W2/W1 columns cached in registers across rows.
__global__ __launch_bounds__(128) void learner2(
    const float* __restrict__ Xa, const unsigned short* __restrict__ Xb,
    int Ma, int Mtot,
    const void* __restrict__ u, const void* __restrict__ W2,
    const void* __restrict__ W1,
    float* __restrict__ p2a, float* __restrict__ p1a,
    unsigned short* __restrict__ w2me, unsigned short* __restrict__ p1b,
    const float* __restrict__ base, const int* __restrict__ dflag)
{
  __shared__ float sX[128];
  __shared__ float st[16];
  __shared__ float sw[16];
  const bool wf32 = (*dflag) != 0;
  const int t = threadIdx.x;
  const int l = t>>3, j = t&7;
  float uc[16], w2c[16], w1c[16];
#pragma unroll
  for (int m=0;m<16;m++) uc[m] = gld(u, (size_t)l*128 + j*16 + m, wf32);
#pragma unroll
  for (int i=0;i<16;i++) w2c[i] = gld(W2, (size_t)i*128 + t, wf32);
  if (t < 8){
#pragma unroll
    for (int i=0;i<16;i++) w1c[i] = gld(W1, (size_t)i*8 + t, wf32);
  }
  for (int rr=0; rr<4; rr++){
    int row = blockIdx.x*4 + rr;
    if (row >= Mtot) break;
    const bool isB = (row >= Ma);
    const int m = isB ? (row - Ma) : row;
    if (isB) sX[t] = b2f(Xb[(size_t)m*DD + t]);
    else     sX[t] = Xa[(size_t)m*DD + t];
    __syncthreads();
    float part = 0.f;
#pragma unroll
    for (int mm=0;mm<16;mm++) part += sX[j*16+mm]*uc[mm];
    part += __shfl_xor(part,1,64); part += __shfl_xor(part,2,64); part += __shfl_xor(part,4,64);
    if (j==0) st[l] = part * 0.08838834764831845f;
    __syncthreads();
    float mx=-1e30f;
    for (int i=0;i<16;i++) mx = fmaxf(mx, st[i]);
    float ssum=0.f;
    for (int i=0;i<16;i++) ssum += __expf(st[i]-mx);
    float inv = 1.f/ssum;
    if (t<16) sw[t] = __expf(st[t]-mx)*inv;
    __syncthreads();
    float a=0.f;
#pragma unroll
    for (int i=0;i<16;i++) a += sw[i]*w2c[i];
    if (isB) w2me[(size_t)m*DD+t] = f2b(base[152+t] + a);
    else     p2a[(size_t)m*DD+t] = a;
    if (t<8){
      float bb=0.f;
#pragma unroll
      for (int i=0;i<16;i++) bb += sw[i]*w1c[i];
      if (isB) p1b[(size_t)m*HH+t] = f2b(bb);
      else     p1a[(size_t)m*HH+t] = bb;
    }
    __syncthreads();
  }
}

// ---------------- big-graph: fused scores+agg, fp8 kv, packed indices ----------
// ONE 8-lane group per dst node = ONE HEAD PER LANE (16 channels). Score dot is
// fully lane-local (zero shuffles); per-lane softmax state; 8 independent
// gather streams per wave. Q head-scale (base_n2 + p2mn[mnid]) applied here
// (deferred from the QKV gemm). agg PRE-NORMALIZED (0.125 fp8 v-descale folded
// into 1/z).
__global__ __launch_bounds__(256) void edge_fused(
    const int* __restrict__ rowptr, const int* __restrict__ epack,
    const int* __restrict__ mnid,
    const unsigned short* __restrict__ q, const unsigned char* __restrict__ kv8,
    const unsigned short* __restrict__ w2me, const unsigned short* __restrict__ p1me,
    const float* __restrict__ p1mn, const float* __restrict__ p2mn,
    const float* __restrict__ base,
    unsigned short* __restrict__ aggb, int N)
{
  const int tid = threadIdx.x;
  const int lane = tid & 63;
  const int l8 = lane & 7;                  // head index
  const int d = blockIdx.x*32 + (tid>>6)*8 + (lane>>3);
  if (d >= N) return;
  const int h = l8;
  const int c16 = l8*16;                    // channel base
  const int i0 = rowptr[d], i1 = rowptr[d+1];
  const int mn = mnid[d];
  const float bias = base[16+h] + base[8+h] + p1mn[(size_t)mn*HH + h];
  const size_t dq = (size_t)d*DD;

  float qv[16];
  {
    uint4 qr0 = *(const uint4*)(q + dq + c16);
    uint4 qr1 = *(const uint4*)(q + dq + c16 + 8);
    const unsigned short* qh0 = (const unsigned short*)&qr0;
    const unsigned short* qh1 = (const unsigned short*)&qr1;
    const float* p2 = p2mn + (size_t)mn*DD + c16;
    const float* sv = base + 24 + c16;      // base_n2
#pragma unroll
    for (int j=0;j<8;j++) qv[j]   = b2f(qh0[j]) * (sv[j]   + p2[j])   * 0.03125f;
#pragma unroll
    for (int j=0;j<8;j++) qv[8+j] = b2f(qh1[j]) * (sv[8+j] + p2[8+j]) * 0.03125f;
  }

  float zh = 0.f;
  float a[16];
#pragma unroll
  for (int j=0;j<16;j++) a[j] = 0.f;

  int i = i0;
  for (; i + 1 < i1; i += 2){
    unsigned int v0p = (unsigned int)epack[i];
    unsigned int v1p = (unsigned int)epack[i+1];
    int s0 = v0p & 0x1FFFF, me0 = v0p >> 17;
    int s1 = v1p & 0x1FFFF, me1 = v1p >> 17;
    const unsigned char* kv0 = kv8 + (size_t)s0*256 + c16;
    const unsigned char* kv1 = kv8 + (size_t)s1*256 + c16;
    const unsigned short* w0 = w2me + (size_t)me0*DD + c16;
    const unsigned short* w1 = w2me + (size_t)me1*DD + c16;
    uint4 kraw0 = *(const uint4*)kv0;
    uint4 vraw0 = *(const uint4*)(kv0 + 128);
    us8 w0a = *(const us8*)w0;
    us8 w0b = *(const us8*)(w0 + 8);
    float pm0 = b2f(p1me[(size_t)me0*HH + h]);
    uint4 kraw1 = *(const uint4*)kv1;
    uint4 vraw1 = *(const uint4*)(kv1 + 128);
    us8 w1a = *(const us8*)w1;
    us8 w1b = *(const us8*)(w1 + 8);
    float pm1 = b2f(p1me[(size_t)me1*HH + h]);

    float k0f[16], k1f[16];
    cvt4(kraw0.x,k0f);   cvt4(kraw0.y,k0f+4);
    cvt4(kraw0.z,k0f+8); cvt4(kraw0.w,k0f+12);
    cvt4(kraw1.x,k1f);   cvt4(kraw1.y,k1f+4);
    cvt4(kraw1.z,k1f+8); cvt4(kraw1.w,k1f+12);
    float pA = 0.f, pB = 0.f;
#pragma unroll
    for (int j=0;j<8;j++){
      pA += qv[j]  *(k0f[j]  *b2f(w0a.s[j]));
      pA += qv[8+j]*(k0f[8+j]*b2f(w0b.s[j]));
      pB += qv[j]  *(k1f[j]  *b2f(w1a.s[j]));
      pB += qv[8+j]*(k1f[8+j]*b2f(w1b.s[j]));
    }
    float ex0 = __expf(pA + bias + pm0);
    float ex1 = __expf(pB + bias + pm1);
    zh += ex0 + ex1;
    float v0f[16], v1f[16];
    cvt4(vraw0.x,v0f);   cvt4(vraw0.y,v0f+4);
    cvt4(vraw0.z,v0f+8); cvt4(vraw0.w,v0f+12);
    cvt4(vraw1.x,v1f);   cvt4(vraw1.y,v1f+4);
    cvt4(vraw1.z,v1f+8); cvt4(vraw1.w,v1f+12);
#pragma unroll
    for (int j=0;j<16;j++) a[j] += ex0*v0f[j] + ex1*v1f[j];
  }
  if (i < i1){
    unsigned int vp = (unsigned int)epack[i];
    int s = vp & 0x1FFFF, me = vp >> 17;
    const unsigned char* kv0 = kv8 + (size_t)s*256 + c16;
    const unsigned short* w0 = w2me + (size_t)me*DD + c16;
    uint4 kraw = *(const uint4*)kv0;
    uint4 vraw = *(const uint4*)(kv0 + 128);
    us8 wa = *(const us8*)w0;
    us8 wb = *(const us8*)(w0 + 8);
    float pm = b2f(p1me[(size_t)me*HH + h]);
    float kf[16];
    cvt4(kraw.x,kf);   cvt4(kraw.y,kf+4);
    cvt4(kraw.z,kf+8); cvt4(kraw.w,kf+12);
    float p = 0.f;
#pragma unroll
    for (int j=0;j<8;j++){
      p += qv[j]  *(kf[j]  *b2f(wa.s[j]));
      p += qv[8+j]*(kf[8+j]*b2f(wb.s[j]));
    }
    float ex = __expf(p + bias + pm);
    zh += ex;
    float vf[16];
    cvt4(vraw.x,vf);   cvt4(vraw.y,vf+4);
    cvt4(vraw.z,vf+8); cvt4(vraw.w,vf+12);
#pragma unroll
    for (int j=0;j<16;j++) a[j] += ex*vf[j];
  }

  float inv = 0.125f / (zh + 1e-9f);        // fp8 v-descale folded into 1/z
  us8 o0, o1;
#pragma unroll
  for (int j=0;j<8;j++){ o0.s[j] = f2b(a[j]*inv); o1.s[j] = f2b(a[8+j]*inv); }
  *(us8*)(aggb + dq + c16)     = o0;
  *(us8*)(aggb + dq + c16 + 8) = o1;
}

// One 16-lane group per target; vectorized feat row read + shuffle reduce.
__global__ __launch_bounds__(256) void readout(
    const int* __restrict__ tgt, const int* __restrict__ mnid,
    const unsigned short* __restrict__ featb, const float* __restrict__ p1mn,
    const float* __restrict__ base, float* __restrict__ acc,
    void* __restrict__ out, int last, float invNB, int BT,
    const int* __restrict__ dflag)
{
  int t = blockIdx.x*256 + threadIdx.x;
  int ti = t >> 4, l16 = t & 15;
  if (ti >= BT) return;
  int idx = tgt[ti]; int mn = mnid[idx];
  int h = l16 >> 1;
  float tw = base[h] + p1mn[(size_t)mn*HH + h];
  uint4 raw = *(const uint4*)(featb + (size_t)idx*DD + l16*8);
  const unsigned short* hw = (const unsigned short*)&raw;
  float s = 0.f;
#pragma unroll
  for (int j=0;j<8;j++) s += b2f(hw[j]);
  float part = tw * s;
  part += __shfl_xor(part, 1, 64);
  part += __shfl_xor(part, 2, 64);
  part += __shfl_xor(part, 4, 64);
  part += __shfl_xor(part, 8, 64);
  if (l16 == 0){
    if (!last) acc[ti] = part;
    else {
      float r = (acc[ti] + part) * invNB;
      if ((*dflag) != 0) ((float*)out)[ti] = r;
      else ((__hip_bfloat16*)out)[ti] = __float2bfloat16(r);
    }
  }
}

extern "C" void kernel_launch(void* const* d_in, const int* in_sizes, int n_in,
                              void* d_out, int out_size, void* d_ws, size_t ws_size,
                              hipStream_t stream) {
  const void* emb   = d_in[0];
  const void* u     = d_in[1];
  const void* W2lat = d_in[2];
  const void* W1lat = d_in[3];
  WPtrs wptrs;
  for (int i=0;i<8;i++) wptrs.p[i] = d_in[4+i];
  const int* node_vals      = (const int*)d_in[12];
  const int* meta_node_vals = (const int*)d_in[13];
  const int* src            = (const int*)d_in[14];
  const int* dst            = (const int*)d_in[15];
  const int* meta_src       = (const int*)d_in[16];
  const int* meta_dst       = (const int*)d_in[17];
  const int* meta_node_id   = (const int*)d_in[18];
  const int* meta_edge_id   = (const int*)d_in[19];
  const int* target_idx     = (const int*)d_in[20];
  const int* static_vals    = (const int*)d_in[21];
  const int* static_src     = (const int*)d_in[22];
  const int* static_dst     = (const int*)d_in[23];

  const int N  = in_sizes[12];
  const int MN = in_sizes[13];
  const int E  = in_sizes[14];
  const int ME = in_sizes[16];
  const int BT = in_sizes[20];
  const int NSRC = in_sizes[22];
  const int NB = in_sizes[8] / (DD*DD);

  float* ws = (float*)d_ws;
  size_t off = 0;
  // keep every allocation 16B-aligned (global_load_lds sources need it)
  auto allocf = [&](size_t n){ float* p = ws + off; off += (n + 3) & ~(size_t)3; return p; };
  auto allocb = [&](size_t n){ unsigned short* p = (unsigned short*)(ws + off); off += (((n+1)/2) + 3) & ~(size_t)3; return p; };
  auto alloci = [&](size_t n){ int* p = (int*)(ws + off); off += (n + 3) & ~(size_t)3; return p; };
  int*            dflag = (int*)ws; off += 4;
  unsigned short* feat  = allocb((size_t)N*DD);
  unsigned short* q     = allocb((size_t)N*DD);
  unsigned char*  kv8   = (unsigned char*)allocf((size_t)N*64);  // N x 256B fp8 rows
  unsigned short* aggb  = allocb((size_t)N*DD);
  float*          meta_feat= allocf((size_t)MN*DD);
  float*          agg_m = allocf((size_t)MN*DD);
  unsigned short* q_m   = allocb((size_t)MN*DD);
  unsigned short* kf_m  = allocb((size_t)MN*DD);
  unsigned short* v_m   = allocb((size_t)MN*DD);
  float*          meta_out = allocf((size_t)MN*DD);
  unsigned short* mef   = allocb((size_t)ME*DD);
  float*          p2mn  = allocf((size_t)MN*DD);
  float*          p1mn  = allocf((size_t)MN*HH);
  unsigned short* w2me  = allocb((size_t)ME*DD);
  unsigned short* p1me  = allocb((size_t)ME*HH);
  float*          base  = allocf(280);
  float*          acc   = allocf((size_t)BT);
  unsigned short* wstage= allocb((size_t)8*NB*DD*DD);
  int*            rowptr= alloci((size_t)N+1);
  int*            cursor= alloci((size_t)N);
  int*            epack = alloci((size_t)E);
  int*            rowptr_m= alloci((size_t)MN+1);
  int*            cursor_m= alloci((size_t)MN);
  int*            esrc_m  = alloci((size_t)ME);
  int*            eorig_m = alloci((size_t)ME);
  int*            degAll  = alloci((size_t)(N+MN));
  int*            deg     = degAll;
  int*            deg_m   = degAll + N;
  const int nb_scan   = (N + 1023)/1024;
  const int nb_scan_m = (MN + 1023)/1024;
  int*            bsum   = alloci((size_t)nb_scan);
  int*            bsum_m = alloci((size_t)nb_scan_m);
  (void)ws_size; (void)n_in; (void)out_size;

  const float* base_n2 = base + 24;

  k_static<<<1,256,0,stream>>>(emb, static_vals, static_src, static_dst,
                               u, W2lat, W1lat, base, NSRC, dflag);
  gather_rows2<<<((N+MN)*16+255)/256,256,0,stream>>>(emb, node_vals, feat, N,
      meta_node_vals, meta_feat, MN, dflag);

  const int nbE  = (E+255)/256, nbME = (ME+255)/256;
  const int nb3B = (N+255)/256, nb3M = (MN+255)/256;
  zeroi<<<(N+MN+255)/256,256,0,stream>>>(degAll, N+MN);
  k_hist2<<<nbE+nbME,256,0,stream>>>(dst, meta_dst, deg, deg_m, E, ME, nbE);
  k_scan1b<<<nb_scan+nb_scan_m,256,0,stream>>>(deg, rowptr, bsum, N, nb_scan,
      deg_m, rowptr_m, bsum_m, MN);
  k_scan3b<<<nb3B+nb3M,256,0,stream>>>(rowptr, bsum, cursor, N, nb3B, nb_scan,
      rowptr_m, bsum_m, cursor_m, MN, nb_scan_m);
  k_scatter2<<<nbE+nbME,256,0,stream>>>(dst, src, meta_edge_id, cursor,
      epack, E, nbE, meta_dst, meta_src, cursor_m, esrc_m, eorig_m, ME);

  w_repack16<<<8*NB*64,256,0,stream>>>(wptrs, wstage, NB, dflag);

  const int gm = (MN+63)/64;
  const int gN = (N+63)/64;
  const float invNB = 1.0f/(float)NB;

  for (int b=0;b<NB;b++){
    const unsigned short* wq_m = wstage + (size_t)(0*NB+b)*DD*DD;
    const unsigned short* wk_m = wstage + (size_t)(1*NB+b)*DD*DD;
    const unsigned short* wv_m = wstage + (size_t)(2*NB+b)*DD*DD;
    const unsigned short* wo_m = wstage + (size_t)(3*NB+b)*DD*DD;
    const unsigned short* wqb  = wstage + (size_t)(4*NB+b)*DD*DD;
    const unsigned short* wkb  = wstage + (size_t)(5*NB+b)*DD*DD;
    const unsigned short* wvb  = wstage + (size_t)(6*NB+b)*DD*DD;
    const unsigned short* wob  = wstage + (size_t)(7*NB+b)*DD*DD;

    // ---- merged big+meta QKV (big q-scale deferred to edge_fused) ----
    gemm_qkv2<<<gN+gm,256,0,stream>>>(feat, meta_feat,
        wqb, wkb, wvb, wq_m, wk_m, wv_m,
        q, kv8, q_m, kf_m, v_m, N, MN, gN, base_n2);

    // ---- meta conv (CSR, atomic-free) ----
    edge_meta_csr<<<(MN+3)/4,256,0,stream>>>(rowptr_m, esrc_m, eorig_m,
        q_m, kf_m, v_m, base, mef, agg_m, MN);
    // meta Wo: meta_out = relu(agg_m@Wo) (f32, agg pre-normalized); meta_feat += relu
    gemm128m<EPI_RELU_RES2,false,false><<<gm,256,0,stream>>>(agg_m, wo_m,
        meta_out, MN, nullptr, meta_feat, meta_feat);
    // wide fused learners: MN rows (f32 meta_out) + ME rows (bf16 mef)
    learner2<<<(MN+ME+3)/4,128,0,stream>>>(meta_out, mef, MN, MN+ME,
        u, W2lat, W1lat, p2mn, p1mn, w2me, p1me, base, dflag);

    // ---- big conv (fp8 kv, one head per lane) ----
    edge_fused<<<(N+31)/32,256,0,stream>>>(rowptr, epack,
        meta_node_id, q, kv8, w2me, p1me, p1mn, p2mn, base, aggb, N);
    gemm128m<EPI_RELU_RES,true,true><<<gN,256,0,stream>>>(aggb, wob, feat, N,
        feat, nullptr, nullptr);

    // ---- readout ----
    readout<<<(BT*16+255)/256,256,0,stream>>>(target_idx, meta_node_id, feat, p1mn,
        base, acc, d_out, (b==NB-1) ? 1 : 0, invNB, BT, dflag);
  }
}

// Round 4
// 571.912 us; speedup vs baseline: 1.2186x; 1.0034x over previous
//
#include <hip/hip_runtime.h>
#include <hip/hip_bf16.h>
#include <hip/hip_fp8.h>

#define DD   128
#define HH   8

typedef short bf16x8 __attribute__((ext_vector_type(8)));
typedef float f32x4  __attribute__((ext_vector_type(4)));
typedef float f32x2  __attribute__((ext_vector_type(2)));

__device__ __forceinline__ float b2f(unsigned short v){
  union { unsigned int u; float f; } x; x.u = ((unsigned int)v) << 16; return x.f;
}
__device__ __forceinline__ unsigned short f2b(float f){
  __hip_bfloat16 h = __float2bfloat16(f);
  return *(unsigned short*)&h;
}
__device__ __forceinline__ unsigned char f2f8(float x){
  __hip_fp8_e4m3 h(x);
  return h.__x;
}
__device__ __forceinline__ float f82f(unsigned char b){
  __hip_fp8_e4m3 h; h.__x = b;
  return (float)h;
}
// 4 fp8 bytes (one u32) -> 4 floats; HW packed cvt when available.
__device__ __forceinline__ void cvt4(unsigned int w, float* o){
#if defined(__has_builtin)
# if __has_builtin(__builtin_amdgcn_cvt_pk_f32_fp8)
  f32x2 lo = __builtin_amdgcn_cvt_pk_f32_fp8((int)w, false);
  f32x2 hi = __builtin_amdgcn_cvt_pk_f32_fp8((int)w, true);
  o[0]=lo[0]; o[1]=lo[1]; o[2]=hi[0]; o[3]=hi[1];
  return;
# endif
#endif
  o[0]=f82f(w&0xff); o[1]=f82f((w>>8)&0xff);
  o[2]=f82f((w>>16)&0xff); o[3]=f82f((w>>24)&0xff);
}
struct __align__(8) us4 { unsigned short x,y,z,w; };
struct __align__(16) us8 { unsigned short s[8]; };

__device__ __forceinline__ float gld(const void* p, size_t i, bool f32){
  if (f32) return ((const float*)p)[i];
  return b2f(((const unsigned short*)p)[i]);
}

// async global->LDS, 16B per lane (wave-uniform LDS base + lane*16)
__device__ __forceinline__ void gll16(const void* g, void* l){
  __builtin_amdgcn_global_load_lds(
      (const __attribute__((address_space(1))) unsigned int*)g,
      (__attribute__((address_space(3))) unsigned int*)l, 16, 0, 0);
}

// ALL weight blocks (8 tensors x NB matrices) -> bf16 TRANSPOSED staging, one launch.
struct WPtrs { const void* p[8]; };
__global__ __launch_bounds__(256) void w_repack16(
    WPtrs W, unsigned short* __restrict__ stage, int NBt,
    const int* __restrict__ dflag)
{
  const bool wf32 = (*dflag) != 0;
  int idx = blockIdx.x >> 6;
  int ti = idx / NBt, bi = idx - ti*NBt;
  size_t bo = (size_t)bi*DD*DD;
  int i = (blockIdx.x & 63)*256 + threadIdx.x;
  int k = i >> 7, n = i & 127;
  float x;
  if (wf32) x = ((const float*)W.p[ti])[bo + i];
  else      x = b2f(((const unsigned short*)W.p[ti])[bo + i]);
  stage[(size_t)idx*DD*DD + n*DD + k] = f2b(x);
}

enum { EPI_STORE=0, EPI_SCALE_CONST=1, EPI_RELU=3,
       EPI_RELU_RES=4, EPI_RELU_RES2=5 };

#define CPAD 132

// ===== shared GEMM building blocks: linear LDS + XOR chunk swizzle =====
// LDS layout: row r (128 bf16 = 256B = 16 chunks of 16B); logical chunk c is
// stored at chunk c ^ (r&7).  Written either by global_load_lds with the
// inverse-swizzled per-lane GLOBAL address (linear LDS dest), or by ds_write
// at the swizzled offset.  Fragment reads use offset  kk ^ ((am&7)<<3).

// C[M,128] = epi( A[M,128] @ B[128,128] ), B bf16 TRANSPOSED ([n][k]).
// EPI_RELU_RES : C = relu(x) + Rb(bf16)                  [big Wo, OUTB=1]
// EPI_RELU_RES2: Cv = relu(x) f32; C2 = relu(x)+Rf (f32) [meta Wo, OUTB=0]
template<int EPI, bool INB, bool OUTB>
__global__ __launch_bounds__(256) void gemm128m(
    const void* __restrict__ Av, const unsigned short* __restrict__ Bt,
    void* __restrict__ Cv, int M,
    const unsigned short* __restrict__ Rb,
    const float* __restrict__ Rf, float* __restrict__ C2)
{
  __shared__ __align__(16) unsigned short Asb[64*128];
  __shared__ __align__(16) unsigned short Btb[16896];  // B: 32KB / C: 64x132 f32
  const int tid = threadIdx.x;
  const int wave = tid >> 6, lane = tid & 63;
  const int row0 = blockIdx.x * 64;

  if (INB){
    const char* Ab = (const char*)Av;
    int n4 = lane >> 4, c = lane & 15;
#pragma unroll
    for (int op=0; op<4; op++){
      int rA = wave*16 + op*4;
      int n = rA + n4;
      int gr = row0 + n; if (gr >= M) gr = M - 1;
      gll16(Ab + (size_t)gr*256 + ((size_t)((c ^ (n & 7)) << 4)), &Asb[rA*128]);
    }
  } else {
    const float* Af = (const float*)Av;
    int r = tid >> 2, cb = (tid & 3) * 32, rx = (r & 7) << 3;
    int gr = row0 + r;
#pragma unroll
    for (int j=0;j<8;j++){
      int cc = cb + j*4;
      float4 val = make_float4(0.f,0.f,0.f,0.f);
      if (gr < M) val = *(const float4*)(Af + (size_t)gr*DD + cc);
      us4 o; o.x=f2b(val.x); o.y=f2b(val.y); o.z=f2b(val.z); o.w=f2b(val.w);
      *(us4*)&Asb[r*128 + (cc ^ rx)] = o;
    }
  }
  {
    int n4 = lane >> 4, c = lane & 15;
#pragma unroll
    for (int op=0; op<8; op++){
      int rB = wave*32 + op*4;
      int n = rB + n4;
      gll16((const char*)Bt + (size_t)n*256 + ((size_t)((c ^ (n & 7)) << 4)),
            &Btb[rB*128]);
    }
  }
  __syncthreads();

  f32x4 acc[8];
#pragma unroll
  for (int t=0;t<8;t++) acc[t] = (f32x4){0.f,0.f,0.f,0.f};
  const int am = (lane & 15), kq = (lane >> 4) * 8, axr = (am & 7) << 3;
#pragma unroll
  for (int k0=0;k0<128;k0+=32){
    int xo = (k0 + kq) ^ axr;
    bf16x8 a = *(bf16x8*)&Asb[(wave*16 + am)*128 + xo];
#pragma unroll
    for (int t=0;t<8;t++){
      bf16x8 b = *(bf16x8*)&Btb[(t*16 + am)*128 + xo];
      acc[t] = __builtin_amdgcn_mfma_f32_16x16x32_bf16(a, b, acc[t], 0,0,0);
    }
  }
  __syncthreads();
  float* Cls = (float*)Btb;
  {
    int rr = wave*16 + (lane>>4)*4;
    int cc = lane & 15;
#pragma unroll
    for (int t=0;t<8;t++)
#pragma unroll
      for (int r=0;r<4;r++)
        Cls[(rr + r)*CPAD + t*16 + cc] = acc[t][r];
  }
  __syncthreads();

  {
    int r = tid >> 2, cb = (tid & 3) * 32;
    int gr = row0 + r;
    if (gr < M){
#pragma unroll
      for (int j=0;j<8;j++){
        int c = cb + j*4;
        float4 o = *(float4*)&Cls[r*CPAD + c];
        if (EPI == EPI_RELU_RES){
          us4 rb = *(const us4*)(Rb + (size_t)gr*DD + c);
          o.x=fmaxf(o.x,0.f)+b2f(rb.x); o.y=fmaxf(o.y,0.f)+b2f(rb.y);
          o.z=fmaxf(o.z,0.f)+b2f(rb.z); o.w=fmaxf(o.w,0.f)+b2f(rb.w);
        } else if (EPI == EPI_RELU_RES2){
          o.x=fmaxf(o.x,0.f); o.y=fmaxf(o.y,0.f); o.z=fmaxf(o.z,0.f); o.w=fmaxf(o.w,0.f);
          float4 rf = *(const float4*)(Rf + (size_t)gr*DD + c);
          *(float4*)(C2 + (size_t)gr*DD + c) =
              make_float4(o.x+rf.x, o.y+rf.y, o.z+rf.z, o.w+rf.w);
        }
        if (OUTB){
          us4 ob; ob.x=f2b(o.x); ob.y=f2b(o.y); ob.z=f2b(o.z); ob.w=f2b(o.w);
          *(us4*)((unsigned short*)Cv + (size_t)gr*DD + c) = ob;
        } else {
          *(float4*)((float*)Cv + (size_t)gr*DD + c) = o;
        }
      }
    }
  }
}

// Fused Q/K/V gemm body. FP8KV: phases 1/2 write fp8 (x8 scale), 256B/row.
// EPIQ==EPI_SCALE_CONST: phase-0 scaled by svec. EPI_STORE: plain store.
template<int EPIQ, bool INB, bool FP8KV>
__device__ __forceinline__ void qkv_body(
    unsigned short* Asb, unsigned short* Btb, int blk,
    const void* __restrict__ Av,
    const unsigned short* __restrict__ Btq, const unsigned short* __restrict__ Btk,
    const unsigned short* __restrict__ Btv,
    void* __restrict__ Cq, void* __restrict__ Ck, int stK,
    void* __restrict__ Cvo, int stV, int M,
    const float* __restrict__ svec)
{
  const int tid = threadIdx.x;
  const int wave = tid >> 6, lane = tid & 63;
  const int row0 = blk * 64;

  if (INB){
    const char* Ab = (const char*)Av;
    int n4 = lane >> 4, c = lane & 15;
#pragma unroll
    for (int op=0; op<4; op++){
      int rA = wave*16 + op*4;
      int n = rA + n4;
      int gr = row0 + n; if (gr >= M) gr = M - 1;
      gll16(Ab + (size_t)gr*256 + ((size_t)((c ^ (n & 7)) << 4)), &Asb[rA*128]);
    }
  } else {
    const float* Af = (const float*)Av;
    int r = tid >> 2, cb = (tid & 3) * 32, rx = (r & 7) << 3;
    int gr = row0 + r;
#pragma unroll
    for (int j=0;j<8;j++){
      int cc = cb + j*4;
      float4 val = make_float4(0.f,0.f,0.f,0.f);
      if (gr < M) val = *(const float4*)(Af + (size_t)gr*DD + cc);
      us4 o; o.x=f2b(val.x); o.y=f2b(val.y); o.z=f2b(val.z); o.w=f2b(val.w);
      *(us4*)&Asb[r*128 + (cc ^ rx)] = o;
    }
  }

  const unsigned short* Bts[3] = {Btq, Btk, Btv};
  void* Cs[3] = {Cq, Ck, Cvo};
  const int sts[3] = {DD, stK, stV};
  const int am = (lane & 15), kq = (lane >> 4) * 8, axr = (am & 7) << 3;

  for (int ph=0; ph<3; ph++){
    {
      const unsigned short* Bt = Bts[ph];
      int n4 = lane >> 4, c = lane & 15;
#pragma unroll
      for (int op=0; op<8; op++){
        int rB = wave*32 + op*4;
        int n = rB + n4;
        gll16((const char*)Bt + (size_t)n*256 + ((size_t)((c ^ (n & 7)) << 4)),
              &Btb[rB*128]);
      }
    }
    __syncthreads();
    f32x4 acc[8];
#pragma unroll
    for (int t=0;t<8;t++) acc[t] = (f32x4){0.f,0.f,0.f,0.f};
#pragma unroll
    for (int k0=0;k0<128;k0+=32){
      int xo = (k0 + kq) ^ axr;
      bf16x8 a = *(bf16x8*)&Asb[(wave*16 + am)*128 + xo];
#pragma unroll
      for (int t=0;t<8;t++){
        bf16x8 b = *(bf16x8*)&Btb[(t*16 + am)*128 + xo];
        acc[t] = __builtin_amdgcn_mfma_f32_16x16x32_bf16(a, b, acc[t], 0,0,0);
      }
    }
    __syncthreads();
    float* Cls = (float*)Btb;
    {
      int rr = wave*16 + (lane>>4)*4;
      int cc = lane & 15;
#pragma unroll
      for (int t=0;t<8;t++)
#pragma unroll
        for (int r=0;r<4;r++)
          Cls[(rr + r)*CPAD + t*16 + cc] = acc[t][r];
    }
    __syncthreads();
    {
      int r = tid >> 2, cb = (tid & 3) * 32;
      int gr = row0 + r;
      if (gr < M){
#pragma unroll
        for (int j=0;j<8;j++){
          int c = cb + j*4;
          float4 o = *(float4*)&Cls[r*CPAD + c];
          if (ph == 0 && EPIQ == EPI_SCALE_CONST){
            o.x*=svec[c+0]; o.y*=svec[c+1]; o.z*=svec[c+2]; o.w*=svec[c+3];
          }
          if (FP8KV && ph > 0){
            unsigned char* Cb = (unsigned char*)Cs[ph];
            uchar4 ob;
            ob.x=f2f8(o.x*8.f); ob.y=f2f8(o.y*8.f);
            ob.z=f2f8(o.z*8.f); ob.w=f2f8(o.w*8.f);
            *(uchar4*)(Cb + (size_t)gr*256 + c) = ob;
          } else {
            us4 ob; ob.x=f2b(o.x); ob.y=f2b(o.y); ob.z=f2b(o.z); ob.w=f2b(o.w);
            *(us4*)((unsigned short*)Cs[ph] + (size_t)gr*sts[ph] + c) = ob;
          }
        }
      }
    }
    __syncthreads();
  }
}

// Merged big+meta QKV in one dispatch: blocks [0,gN) big graph (bf16 in,
// fp8 kv out, plain q store — head scale deferred to edge_fused);
// blocks [gN, gN+gm) meta graph (f32 in, const-scaled q, bf16 out).
__global__ __launch_bounds__(256) void gemm_qkv2(
    const unsigned short* __restrict__ featB, const float* __restrict__ featM,
    const unsigned short* __restrict__ wqb, const unsigned short* __restrict__ wkb,
    const unsigned short* __restrict__ wvb,
    const unsigned short* __restrict__ wqm, const unsigned short* __restrict__ wkm,
    const unsigned short* __restrict__ wvm,
    unsigned short* __restrict__ qB, unsigned char* __restrict__ kv8,
    unsigned short* __restrict__ qM, unsigned short* __restrict__ kfM,
    unsigned short* __restrict__ vM,
    int Nbig, int Nmeta, int gN, const float* __restrict__ svec)
{
  __shared__ __align__(16) unsigned short Asb[64*128];
  __shared__ __align__(16) unsigned short Btb[16896];
  if (blockIdx.x < gN){
    qkv_body<EPI_STORE,true,true>(Asb, Btb, blockIdx.x, featB,
        wqb, wkb, wvb, qB, kv8, 0, kv8 + 128, 0, Nbig, svec);
  } else {
    qkv_body<EPI_SCALE_CONST,false,false>(Asb, Btb, blockIdx.x - gN, featM,
        wqm, wkm, wvm, qM, kfM, DD, vM, DD, Nmeta, svec);
  }
}

// Static param-name graph -> base params.  (k_detect fused in.)
__global__ __launch_bounds__(256) void k_static(
    const void* __restrict__ emb, const int* __restrict__ svals,
    const int* __restrict__ ssrc, const int* __restrict__ sdst,
    const void* __restrict__ u, const void* __restrict__ W2,
    const void* __restrict__ W1, float* __restrict__ base, int nsrc,
    int* __restrict__ dflag)
{
  __shared__ float sagg[15][128];
  __shared__ float ssc[15][16];
  __shared__ float sww[15][16];
  __shared__ int swf;
  const int t = threadIdx.x;
  if (t < 64){
    float m = 0.f;
    for (int i=t; i<128; i+=64){
      float x = fabsf(b2f(((const unsigned short*)emb)[i]));
      if (x < 1e30f) m = fmaxf(m, x);
    }
#pragma unroll
    for (int s=1;s<64;s<<=1) m = fmaxf(m, __shfl_xor(m, s, 64));
    if (t==0){ int f = (m > 1e4f) ? 1 : 0; *dflag = f; swf = f; }
  }
  for (int i=t;i<15*128;i+=256) ((float*)sagg)[i]=0.f;
  __syncthreads();
  const bool wf32 = (swf != 0);
  if (t < 128){
    for (int i=0;i<nsrc;i++){
      int row = sdst[i]; int vr = svals[ssrc[i]];
      sagg[row][t] += gld(emb, (size_t)vr*DD + t, wf32);
    }
  }
  __syncthreads();
  if (t < 240){
    int n = t>>4, l = t&15;
    float a=0.f;
    for (int d=0;d<128;d++) a += sagg[n][d]*gld(u, l*128+d, wf32);
    ssc[n][l] = a * 0.08838834764831845f;
  }
  __syncthreads();
  if (t < 15){
    float mx=-1e30f;
    for (int l=0;l<16;l++) mx = fmaxf(mx, ssc[t][l]);
    float s=0.f;
    for (int l=0;l<16;l++){ float e=__expf(ssc[t][l]-mx); sww[t][l]=e; s+=e; }
    float inv = 1.f/s;
    for (int l=0;l<16;l++) sww[t][l]*=inv;
  }
  __syncthreads();
  if (t < 8){
    float a=0.f,b=0.f,c=0.f;
    for (int l=0;l<16;l++){
      float wv = gld(W1, l*8+t, wf32);
      a += sww[0][l]*wv; b += sww[3][l]*wv; c += sww[9][l]*wv;
    }
    base[t]=a; base[8+t]=b; base[16+t]=c;
  }
  if (t < 128){
    float a=0.f,b=0.f;
    for (int l=0;l<16;l++){
      float wv = gld(W2, l*128+t, wf32);
      a += sww[6][l]*wv; b += sww[12][l]*wv;
    }
    base[24+t]=a; base[152+t]=b;
  }
}

// Merged gather: big graph rows -> bf16 feat; meta rows -> f32 meta_feat.
__global__ __launch_bounds__(256) void gather_rows2(
    const void* __restrict__ emb,
    const int* __restrict__ valsB, unsigned short* __restrict__ featB, int nB,
    const int* __restrict__ valsM, float* __restrict__ featM, int nM,
    const int* __restrict__ dflag)
{
  const bool wf32 = (*dflag) != 0;
  int i = blockIdx.x*256 + threadIdx.x;
  bool big = (i < nB*16);
  int i2 = big ? i : (i - nB*16);
  if (!big && i2 >= nM*16) return;
  int r = i2>>4, c = (i2&15)*8;
  int vr = big ? valsB[r] : valsM[r];
  float vb[8];
  if (wf32){
    float4 f0 = *(const float4*)((const float*)emb + (size_t)vr*DD + c);
    float4 f1 = *(const float4*)((const float*)emb + (size_t)vr*DD + c + 4);
    vb[0]=f0.x; vb[1]=f0.y; vb[2]=f0.z; vb[3]=f0.w;
    vb[4]=f1.x; vb[5]=f1.y; vb[6]=f1.z; vb[7]=f1.w;
  } else {
    uint4 raw = *(const uint4*)((const unsigned short*)emb + (size_t)vr*DD + c);
    const unsigned short* hw = (const unsigned short*)&raw;
#pragma unroll
    for (int j=0;j<8;j++) vb[j] = b2f(hw[j]);
  }
  if (big){
    unsigned short* d = featB + (size_t)r*DD + c;
    us4 o0, o1;
    o0.x=f2b(vb[0]); o0.y=f2b(vb[1]); o0.z=f2b(vb[2]); o0.w=f2b(vb[3]);
    o1.x=f2b(vb[4]); o1.y=f2b(vb[5]); o1.z=f2b(vb[6]); o1.w=f2b(vb[7]);
    *(us4*)d = o0; *(us4*)(d+4) = o1;
  } else {
    float* d = featM + (size_t)r*DD + c;
    *(float4*)d     = make_float4(vb[0],vb[1],vb[2],vb[3]);
    *(float4*)(d+4) = make_float4(vb[4],vb[5],vb[6],vb[7]);
  }
}

__global__ __launch_bounds__(256) void zeroi(int* __restrict__ p, int n){
  int i = blockIdx.x*256 + threadIdx.x;
  if (i < n) p[i] = 0;
}

// ---------------- merged CSR build (big + meta graphs) ----------------
__global__ __launch_bounds__(256) void k_hist2(
    const int* __restrict__ dstB, const int* __restrict__ dstM,
    int* __restrict__ degB, int* __restrict__ degM, int E, int ME, int nbE){
  int b = blockIdx.x, t = threadIdx.x;
  if (b < nbE){ int i = b*256+t; if (i < E) atomicAdd(&degB[dstB[i]], 1); }
  else { int i = (b-nbE)*256+t; if (i < ME) atomicAdd(&degM[dstM[i]], 1); }
}

__global__ __launch_bounds__(256) void k_scan1b(
    const int* __restrict__ degB, int* __restrict__ rpB, int* __restrict__ bsB,
    int nB, int nbB,
    const int* __restrict__ degM, int* __restrict__ rpM, int* __restrict__ bsM,
    int nM){
  __shared__ int ls[256];
  int blk = blockIdx.x, t = threadIdx.x;
  const int* deg; int* rowptr; int* bsum; int n; int b;
  if (blk < nbB){ deg=degB; rowptr=rpB; bsum=bsB; n=nB; b=blk; }
  else          { deg=degM; rowptr=rpM; bsum=bsM; n=nM; b=blk-nbB; }
  int base = b*1024 + t*4;
  int v0 = (base+0<n)?deg[base+0]:0;
  int v1 = (base+1<n)?deg[base+1]:0;
  int v2 = (base+2<n)?deg[base+2]:0;
  int v3 = (base+3<n)?deg[base+3]:0;
  int tsum = v0+v1+v2+v3;
  ls[t] = tsum; __syncthreads();
  for (int o=1;o<256;o<<=1){
    int x = (t>=o) ? ls[t-o] : 0;
    __syncthreads();
    ls[t] += x;
    __syncthreads();
  }
  int excl = ls[t]-tsum;
  if (t==255) bsum[b] = ls[255];
  if (base+0<n) rowptr[base+0]=excl;
  if (base+1<n) rowptr[base+1]=excl+v0;
  if (base+2<n) rowptr[base+2]=excl+v0+v1;
  if (base+3<n) rowptr[base+3]=excl+v0+v1+v2;
}

// scan3 with in-block prefix of block sums (scan2 merged in).
__global__ __launch_bounds__(256) void k_scan3b(
    int* __restrict__ rpB, const int* __restrict__ bsB, int* __restrict__ curB,
    int nB, int nb3B, int nbsB,
    int* __restrict__ rpM, const int* __restrict__ bsM, int* __restrict__ curM,
    int nM, int nbsM){
  __shared__ int spre;
  int blk = blockIdx.x, t = threadIdx.x;
  if (blk < nb3B){
    if (t == 0){
      int chunk = blk >> 2;
      int pre = 0;
      for (int j=0;j<chunk;j++) pre += bsB[j];
      spre = pre;
      if (blk == 0){
        int tot = 0;
        for (int j=0;j<nbsB;j++) tot += bsB[j];
        rpB[nB] = tot;
      }
    }
    __syncthreads();
    int i = blk*256 + t;
    if (i < nB){ int r = rpB[i] + spre; rpB[i] = r; curB[i] = r; }
  } else {
    int b2 = blk - nb3B;
    if (t == 0){
      int chunk = b2 >> 2;
      int pre = 0;
      for (int j=0;j<chunk;j++) pre += bsM[j];
      spre = pre;
      if (b2 == 0){
        int tot = 0;
        for (int j=0;j<nbsM;j++) tot += bsM[j];
        rpM[nM] = tot;
      }
    }
    __syncthreads();
    int i = b2*256 + t;
    if (i < nM){ int r = rpM[i] + spre; rpM[i] = r; curM[i] = r; }
  }
}

// scatter. Big graph: pack (src | meid<<17) into one int.
__global__ __launch_bounds__(256) void k_scatter2(
    const int* __restrict__ dstB, const int* __restrict__ srcB,
    const int* __restrict__ auxB, int* __restrict__ curB,
    int* __restrict__ epackB, int E, int nbE,
    const int* __restrict__ dstM, const int* __restrict__ srcM,
    int* __restrict__ curM, int* __restrict__ esrcM, int* __restrict__ eauxM,
    int ME){
  int blk = blockIdx.x, t = threadIdx.x;
  if (blk < nbE){
    int e = blk*256 + t;
    if (e < E){
      int p = atomicAdd(&curB[dstB[e]], 1);
      epackB[p] = srcB[e] | (auxB[e] << 17);
    }
  } else {
    int e = (blk-nbE)*256 + t;
    if (e < ME){
      int p = atomicAdd(&curM[dstM[e]], 1);
      esrcM[p] = srcM[e];
      eauxM[p] = e;
    }
  }
}

// ---------------- meta-graph edges: CSR, atomic-free, writes mef ----------------
// agg written PRE-NORMALIZED (softmax denominator folded in here).
__global__ __launch_bounds__(256) void edge_meta_csr(
    const int* __restrict__ rowptr, const int* __restrict__ esrc,
    const int* __restrict__ eorig,
    const unsigned short* __restrict__ qm, const unsigned short* __restrict__ kfm,
    const unsigned short* __restrict__ vm,
    const float* __restrict__ base, unsigned short* __restrict__ mef,
    float* __restrict__ agg, int NM)
{
  int d = blockIdx.x*4 + (threadIdx.x>>6);
  if (d >= NM) return;
  int lane = threadIdx.x & 63;
  const float* be2 = base+152; const float* be1 = base+16; const float* bn1 = base+8;
  size_t dq = (size_t)d*DD;
  float q0 = b2f(qm[dq+lane]), q1 = b2f(qm[dq+64+lane]);
  float w0 = be2[lane], w1 = be2[64+lane];
  int h0 = lane>>4, h1 = h0+4;
  float bias0 = be1[h0] + bn1[h0];
  float bias1 = be1[h1] + bn1[h1];
  float z0=0.f, z1=0.f, a0=0.f, a1=0.f;
  int i0 = rowptr[d], i1 = rowptr[d+1];
  for (int i=i0; i<i1; i++){
    int s = esrc[i], e = eorig[i];
    size_t so=(size_t)s*DD, eo=(size_t)e*DD;
    float ke0 = b2f(kfm[so+lane])    * w0;
    float ke1 = b2f(kfm[so+64+lane]) * w1;
    mef[eo+lane]=f2b(ke0); mef[eo+64+lane]=f2b(ke1);
    float p0 = q0*ke0, p1 = q1*ke1;
#pragma unroll
    for (int m=1;m<16;m<<=1){ p0 += __shfl_xor(p0,m,64); p1 += __shfl_xor(p1,m,64); }
    float e0 = __expf(p0*0.25f + bias0);
    float e1 = __expf(p1*0.25f + bias1);
    z0 += e0; z1 += e1;
    a0 += e0*b2f(vm[so+lane]);
    a1 += e1*b2f(vm[so+64+lane]);
  }
  float inv0 = 1.f/(z0 + 1e-9f);
  float inv1 = 1.f/(z1 + 1e-9f);
  agg[dq+lane]    = a0*inv0;
  agg[dq+64+lane] = a1*inv1;
}

// Fused meta-learner over [meta_out (Ma rows, f32) | mef (bf16)].
// 4 rows per block; u/W2/W1 columns cached in registers across rows.
__global__ __launch_bounds__(128) void learner2(
    const float* __restrict__ Xa, const unsigned short* __restrict__ Xb,
    int Ma, int Mtot,
    const void* __restrict__ u, const void* __restrict__ W2,
    const void* __restrict__ W1,
    float* __restrict__ p2a, float* __restrict__ p1a,
    unsigned short* __restrict__ w2me, unsigned short* __restrict__ p1b,
    const float* __restrict__ base, const int* __restrict__ dflag)
{
  __shared__ float sX[128];
  __shared__ float st[16];
  __shared__ float sw[16];
  const bool wf32 = (*dflag) != 0;
  const int t = threadIdx.x;
  const int l = t>>3, j = t&7;
  float uc[16], w2c[16], w1c[16];
#pragma unroll
  for (int m=0;m<16;m++) uc[m] = gld(u, (size_t)l*128 + j*16 + m, wf32);
#pragma unroll
  for (int i=0;i<16;i++) w2c[i] = gld(W2, (size_t)i*128 + t, wf32);
  if (t < 8){
#pragma unroll
    for (int i=0;i<16;i++) w1c[i] = gld(W1, (size_t)i*8 + t, wf32);
  }
  for (int rr=0; rr<4; rr++){
    int row = blockIdx.x*4 + rr;
    if (row >= Mtot) break;
    const bool isB = (row >= Ma);
    const int m = isB ? (row - Ma) : row;
    if (isB) sX[t] = b2f(Xb[(size_t)m*DD + t]);
    else     sX[t] = Xa[(size_t)m*DD + t];
    __syncthreads();
    float part = 0.f;
#pragma unroll
    for (int mm=0;mm<16;mm++) part += sX[j*16+mm]*uc[mm];
    part += __shfl_xor(part,1,64); part += __shfl_xor(part,2,64); part += __shfl_xor(part,4,64);
    if (j==0) st[l] = part * 0.08838834764831845f;
    __syncthreads();
    float mx=-1e30f;
    for (int i=0;i<16;i++) mx = fmaxf(mx, st[i]);
    float ssum=0.f;
    for (int i=0;i<16;i++) ssum += __expf(st[i]-mx);
    float inv = 1.f/ssum;
    if (t<16) sw[t] = __expf(st[t]-mx)*inv;
    __syncthreads();
    float a=0.f;
#pragma unroll
    for (int i=0;i<16;i++) a += sw[i]*w2c[i];
    if (isB) w2me[(size_t)m*DD+t] = f2b(base[152+t] + a);
    else     p2a[(size_t)m*DD+t] = a;
    if (t<8){
      float bb=0.f;
#pragma unroll
      for (int i=0;i<16;i++) bb += sw[i]*w1c[i];
      if (isB) p1b[(size_t)m*HH+t] = f2b(bb);
      else     p1a[(size_t)m*HH+t] = bb;
    }
    __syncthreads();
  }
}

// ---------------- big-graph: fused scores+agg, fp8 kv, packed indices ----------
// ONE 16-lane group per dst node (4 nodes/wave, best measured occupancy point);
// 4-edge software pipeline: all 4 edges' index+k+v+w loads issued before the
// 4 compute steps (doubles in-flight gathers vs 2-deep). Q head-scale
// (base_n2 + p2mn[mnid], L2-resident) applied here — deferred from QKV gemm.
// agg PRE-NORMALIZED (0.125 fp8 v-descale folded into 1/z; no z round-trip).
__global__ __launch_bounds__(256) void edge_fused(
    const int* __restrict__ rowptr, const int* __restrict__ epack,
    const int* __restrict__ mnid,
    const unsigned short* __restrict__ q, const unsigned char* __restrict__ kv8,
    const unsigned short* __restrict__ w2me, const unsigned short* __restrict__ p1me,
    const float* __restrict__ p1mn, const float* __restrict__ p2mn,
    const float* __restrict__ base,
    unsigned short* __restrict__ aggb, int N)
{
  int wv = blockIdx.x*4 + (threadIdx.x>>6);
  int lane = threadIdx.x & 63;
  int grp = lane >> 4, l16 = lane & 15;
  int d = wv*4 + grp;                 // each 16-lane group owns one dst node
  if (d >= N) return;
  int c8 = l16 * 8;
  int h = l16 >> 1;

  int i0 = rowptr[d], i1 = rowptr[d+1];
  int mn = mnid[d];
  float bias = base[16+h] + base[8+h] + p1mn[(size_t)mn*HH + h];
  size_t dq = (size_t)d*DD;
  float qv[8];
  {
    uint4 qraw = *(const uint4*)(q + dq + c8);
    const unsigned short* qh = (const unsigned short*)&qraw;
    const float* p2 = p2mn + (size_t)mn*DD + c8;
    const float* sv = base + 24 + c8;       // base_n2
#pragma unroll
    for (int j=0;j<8;j++) qv[j] = b2f(qh[j]) * (sv[j] + p2[j]) * 0.03125f; // 0.25/8
  }

  float zh = 0.f;
  float a[8];
#pragma unroll
  for (int j=0;j<8;j++) a[j] = 0.f;

  int i = i0;
  // 4-deep pipelined main loop
  for (; i + 3 < i1; i += 4){
    uint2 kr[4], vr[4]; uint4 wr[4]; float pm[4];
#pragma unroll
    for (int t=0;t<4;t++){
      unsigned int vp = (unsigned int)epack[i+t];
      int s = vp & 0x1FFFF, me = vp >> 17;
      const unsigned char* kv = kv8 + (size_t)s*256 + c8;
      kr[t] = *(const uint2*)kv;
      vr[t] = *(const uint2*)(kv + 128);
      wr[t] = *(const uint4*)(w2me + (size_t)me*DD + c8);
      pm[t] = b2f(p1me[(size_t)me*HH + h]);
    }
#pragma unroll
    for (int t=0;t<4;t++){
      float kf[8], vf[8];
      cvt4(kr[t].x, kf); cvt4(kr[t].y, kf+4);
      cvt4(vr[t].x, vf); cvt4(vr[t].y, vf+4);
      const unsigned short* wh = (const unsigned short*)&wr[t];
      float p = 0.f;
#pragma unroll
      for (int j=0;j<8;j++) p += qv[j]*(kf[j]*b2f(wh[j]));
      p += __shfl_xor(p, 1, 64);
      float ex = __expf(p + bias + pm[t]);
      zh += ex;
#pragma unroll
      for (int j=0;j<8;j++) a[j] += ex*vf[j];
    }
  }
  // 2-deep tail
  for (; i + 1 < i1; i += 2){
    unsigned int v0p = (unsigned int)epack[i];
    unsigned int v1p = (unsigned int)epack[i+1];
    int s0 = v0p & 0x1FFFF, me0 = v0p >> 17;
    int s1 = v1p & 0x1FFFF, me1 = v1p >> 17;
    const unsigned char* kv0 = kv8 + (size_t)s0*256 + c8;
    const unsigned char* kv1 = kv8 + (size_t)s1*256 + c8;
    uint2 kraw0 = *(const uint2*)kv0;
    uint2 vraw0 = *(const uint2*)(kv0 + 128);
    uint4 wraw0 = *(const uint4*)(w2me + (size_t)me0*DD + c8);
    float pm0 = b2f(p1me[(size_t)me0*HH + h]);
    uint2 kraw1 = *(const uint2*)kv1;
    uint2 vraw1 = *(const uint2*)(kv1 + 128);
    uint4 wraw1 = *(const uint4*)(w2me + (size_t)me1*DD + c8);
    float pm1 = b2f(p1me[(size_t)me1*HH + h]);
    float k0f[8], v0f[8], k1f[8], v1f[8];
    cvt4(kraw0.x, k0f); cvt4(kraw0.y, k0f+4);
    cvt4(vraw0.x, v0f); cvt4(vraw0.y, v0f+4);
    cvt4(kraw1.x, k1f); cvt4(kraw1.y, k1f+4);
    cvt4(vraw1.x, v1f); cvt4(vraw1.y, v1f+4);
    const unsigned short* wh0 = (const unsigned short*)&wraw0;
    const unsigned short* wh1 = (const unsigned short*)&wraw1;
    float pA = 0.f, pB = 0.f;
#pragma unroll
    for (int j=0;j<8;j++){
      pA += qv[j]*(k0f[j]*b2f(wh0[j]));
      pB += qv[j]*(k1f[j]*b2f(wh1[j]));
    }
    pA += __shfl_xor(pA, 1, 64);
    pB += __shfl_xor(pB, 1, 64);
    float ex0 = __expf(pA + bias + pm0);
    float ex1 = __expf(pB + bias + pm1);
    zh += ex0 + ex1;
#pragma unroll
    for (int j=0;j<8;j++) a[j] += ex0*v0f[j] + ex1*v1f[j];
  }
  if (i < i1){
    unsigned int vp = (unsigned int)epack[i];
    int s = vp & 0x1FFFF, me = vp >> 17;
    const unsigned char* kv = kv8 + (size_t)s*256 + c8;
    uint2 kraw = *(const uint2*)kv;
    uint2 vraw = *(const uint2*)(kv + 128);
    uint4 wraw = *(const uint4*)(w2me + (size_t)me*DD + c8);
    float pm = b2f(p1me[(size_t)me*HH + h]);
    float kf[8], vf[8];
    cvt4(kraw.x, kf); cvt4(kraw.y, kf+4);
    cvt4(vraw.x, vf); cvt4(vraw.y, vf+4);
    const unsigned short* wh = (const unsigned short*)&wraw;
    float p = 0.f;
#pragma unroll
    for (int j=0;j<8;j++) p += qv[j]*(kf[j]*b2f(wh[j]));
    p += __shfl_xor(p, 1, 64);
    float ex = __expf(p + bias + pm);
    zh += ex;
#pragma unroll
    for (int j=0;j<8;j++) a[j] += ex*vf[j];
  }

  // each lane owns its 8 channels; zh is per-head (same in both pair lanes)
  float inv = 0.125f / (zh + 1e-9f);   // fp8 v-descale folded into 1/z
  us8 o;
#pragma unroll
  for (int j=0;j<8;j++) o.s[j] = f2b(a[j]*inv);
  *(us8*)(aggb + dq + c8) = o;
}

// One 16-lane group per target; vectorized feat row read + shuffle reduce.
__global__ __launch_bounds__(256) void readout(
    const int* __restrict__ tgt, const int* __restrict__ mnid,
    const unsigned short* __restrict__ featb, const float* __restrict__ p1mn,
    const float* __restrict__ base, float* __restrict__ acc,
    void* __restrict__ out, int last, float invNB, int BT,
    const int* __restrict__ dflag)
{
  int t = blockIdx.x*256 + threadIdx.x;
  int ti = t >> 4, l16 = t & 15;
  if (ti >= BT) return;
  int idx = tgt[ti]; int mn = mnid[idx];
  int h = l16 >> 1;
  float tw = base[h] + p1mn[(size_t)mn*HH + h];
  uint4 raw = *(const uint4*)(featb + (size_t)idx*DD + l16*8);
  const unsigned short* hw = (const unsigned short*)&raw;
  float s = 0.f;
#pragma unroll
  for (int j=0;j<8;j++) s += b2f(hw[j]);
  float part = tw * s;
  part += __shfl_xor(part, 1, 64);
  part += __shfl_xor(part, 2, 64);
  part += __shfl_xor(part, 4, 64);
  part += __shfl_xor(part, 8, 64);
  if (l16 == 0){
    if (!last) acc[ti] = part;
    else {
      float r = (acc[ti] + part) * invNB;
      if ((*dflag) != 0) ((float*)out)[ti] = r;
      else ((__hip_bfloat16*)out)[ti] = __float2bfloat16(r);
    }
  }
}

extern "C" void kernel_launch(void* const* d_in, const int* in_sizes, int n_in,
                              void* d_out, int out_size, void* d_ws, size_t ws_size,
                              hipStream_t stream) {
  const void* emb   = d_in[0];
  const void* u     = d_in[1];
  const void* W2lat = d_in[2];
  const void* W1lat = d_in[3];
  WPtrs wptrs;
  for (int i=0;i<8;i++) wptrs.p[i] = d_in[4+i];
  const int* node_vals      = (const int*)d_in[12];
  const int* meta_node_vals = (const int*)d_in[13];
  const int* src            = (const int*)d_in[14];
  const int* dst            = (const int*)d_in[15];
  const int* meta_src       = (const int*)d_in[16];
  const int* meta_dst       = (const int*)d_in[17];
  const int* meta_node_id   = (const int*)d_in[18];
  const int* meta_edge_id   = (const int*)d_in[19];
  const int* target_idx     = (const int*)d_in[20];
  const int* static_vals    = (const int*)d_in[21];
  const int* static_src     = (const int*)d_in[22];
  const int* static_dst     = (const int*)d_in[23];

  const int N  = in_sizes[12];
  const int MN = in_sizes[13];
  const int E  = in_sizes[14];
  const int ME = in_sizes[16];
  const int BT = in_sizes[20];
  const int NSRC = in_sizes[22];
  const int NB = in_sizes[8] / (DD*DD);

  float* ws = (float*)d_ws;
  size_t off = 0;
  // keep every allocation 16B-aligned (global_load_lds sources need it)
  auto allocf = [&](size_t n){ float* p = ws + off; off += (n + 3) & ~(size_t)3; return p; };
  auto allocb = [&](size_t n){ unsigned short* p = (unsigned short*)(ws + off); off += (((n+1)/2) + 3) & ~(size_t)3; return p; };
  auto alloci = [&](size_t n){ int* p = (int*)(ws + off); off += (n + 3) & ~(size_t)3; return p; };
  int*            dflag = (int*)ws; off += 4;
  unsigned short* feat  = allocb((size_t)N*DD);
  unsigned short* q     = allocb((size_t)N*DD);
  unsigned char*  kv8   = (unsigned char*)allocf((size_t)N*64);  // N x 256B fp8 rows
  unsigned short* aggb  = allocb((size_t)N*DD);
  float*          meta_feat= allocf((size_t)MN*DD);
  float*          agg_m = allocf((size_t)MN*DD);
  unsigned short* q_m   = allocb((size_t)MN*DD);
  unsigned short* kf_m  = allocb((size_t)MN*DD);
  unsigned short* v_m   = allocb((size_t)MN*DD);
  float*          meta_out = allocf((size_t)MN*DD);
  unsigned short* mef   = allocb((size_t)ME*DD);
  float*          p2mn  = allocf((size_t)MN*DD);
  float*          p1mn  = allocf((size_t)MN*HH);
  unsigned short* w2me  = allocb((size_t)ME*DD);
  unsigned short* p1me  = allocb((size_t)ME*HH);
  float*          base  = allocf(280);
  float*          acc   = allocf((size_t)BT);
  unsigned short* wstage= allocb((size_t)8*NB*DD*DD);
  int*            rowptr= alloci((size_t)N+1);
  int*            cursor= alloci((size_t)N);
  int*            epack = alloci((size_t)E);
  int*            rowptr_m= alloci((size_t)MN+1);
  int*            cursor_m= alloci((size_t)MN);
  int*            esrc_m  = alloci((size_t)ME);
  int*            eorig_m = alloci((size_t)ME);
  int*            degAll  = alloci((size_t)(N+MN));
  int*            deg     = degAll;
  int*            deg_m   = degAll + N;
  const int nb_scan   = (N + 1023)/1024;
  const int nb_scan_m = (MN + 1023)/1024;
  int*            bsum   = alloci((size_t)nb_scan);
  int*            bsum_m = alloci((size_t)nb_scan_m);
  (void)ws_size; (void)n_in; (void)out_size;

  const float* base_n2 = base + 24;

  k_static<<<1,256,0,stream>>>(emb, static_vals, static_src, static_dst,
                               u, W2lat, W1lat, base, NSRC, dflag);
  gather_rows2<<<((N+MN)*16+255)/256,256,0,stream>>>(emb, node_vals, feat, N,
      meta_node_vals, meta_feat, MN, dflag);

  const int nbE  = (E+255)/256, nbME = (ME+255)/256;
  const int nb3B = (N+255)/256, nb3M = (MN+255)/256;
  zeroi<<<(N+MN+255)/256,256,0,stream>>>(degAll, N+MN);
  k_hist2<<<nbE+nbME,256,0,stream>>>(dst, meta_dst, deg, deg_m, E, ME, nbE);
  k_scan1b<<<nb_scan+nb_scan_m,256,0,stream>>>(deg, rowptr, bsum, N, nb_scan,
      deg_m, rowptr_m, bsum_m, MN);
  k_scan3b<<<nb3B+nb3M,256,0,stream>>>(rowptr, bsum, cursor, N, nb3B, nb_scan,
      rowptr_m, bsum_m, cursor_m, MN, nb_scan_m);
  k_scatter2<<<nbE+nbME,256,0,stream>>>(dst, src, meta_edge_id, cursor,
      epack, E, nbE, meta_dst, meta_src, cursor_m, esrc_m, eorig_m, ME);

  w_repack16<<<8*NB*64,256,0,stream>>>(wptrs, wstage, NB, dflag);

  const int gm = (MN+63)/64;
  const int gN = (N+63)/64;
  const float invNB = 1.0f/(float)NB;

  for (int b=0;b<NB;b++){
    const unsigned short* wq_m = wstage + (size_t)(0*NB+b)*DD*DD;
    const unsigned short* wk_m = wstage + (size_t)(1*NB+b)*DD*DD;
    const unsigned short* wv_m = wstage + (size_t)(2*NB+b)*DD*DD;
    const unsigned short* wo_m = wstage + (size_t)(3*NB+b)*DD*DD;
    const unsigned short* wqb  = wstage + (size_t)(4*NB+b)*DD*DD;
    const unsigned short* wkb  = wstage + (size_t)(5*NB+b)*DD*DD;
    const unsigned short* wvb  = wstage + (size_t)(6*NB+b)*DD*DD;
    const unsigned short* wob  = wstage + (size_t)(7*NB+b)*DD*DD;

    // ---- merged big+meta QKV (big q-scale deferred to edge_fused) ----
    gemm_qkv2<<<gN+gm,256,0,stream>>>(feat, meta_feat,
        wqb, wkb, wvb, wq_m, wk_m, wv_m,
        q, kv8, q_m, kf_m, v_m, N, MN, gN, base_n2);

    // ---- meta conv (CSR, atomic-free) ----
    edge_meta_csr<<<(MN+3)/4,256,0,stream>>>(rowptr_m, esrc_m, eorig_m,
        q_m, kf_m, v_m, base, mef, agg_m, MN);
    // meta Wo: meta_out = relu(agg_m@Wo) (f32, agg pre-normalized); meta_feat += relu
    gemm128m<EPI_RELU_RES2,false,false><<<gm,256,0,stream>>>(agg_m, wo_m,
        meta_out, MN, nullptr, meta_feat, meta_feat);
    // wide fused learners: MN rows (f32 meta_out) + ME rows (bf16 mef)
    learner2<<<(MN+ME+3)/4,128,0,stream>>>(meta_out, mef, MN, MN+ME,
        u, W2lat, W1lat, p2mn, p1mn, w2me, p1me, base, dflag);

    // ---- big conv (fp8 kv, 16-lane group per node, 4-deep pipeline) ----
    edge_fused<<<(N+15)/16,256,0,stream>>>(rowptr, epack,
        meta_node_id, q, kv8, w2me, p1me, p1mn, p2mn, base, aggb, N);
    gemm128m<EPI_RELU_RES,true,true><<<gN,256,0,stream>>>(aggb, wob, feat, N,
        feat, nullptr, nullptr);

    // ---- readout ----
    readout<<<(BT*16+255)/256,256,0,stream>>>(target_idx, meta_node_id, feat, p1mn,
        base, acc, d_out, (b==NB-1) ? 1 : 0, invNB, BT, dflag);
  }
}